// Round 7
// baseline (2227.563 us; speedup 1.0000x reference)
//
#include <hip/hip_runtime.h>
#include <cstdint>
#include <cstddef>

#define DIM 512
#define NLAYERS 3
#define GBM 128
#define GBN 128
#define GBK 64

typedef float f32x4 __attribute__((ext_vector_type(4)));
typedef short bf16x8 __attribute__((ext_vector_type(8)));
typedef unsigned short u16x4 __attribute__((ext_vector_type(4)));
typedef unsigned short u16x8 __attribute__((ext_vector_type(8)));

__device__ __forceinline__ unsigned short f32_to_bf16(float f) {
    unsigned u = __float_as_uint(f);
    u += 0x7fffu + ((u >> 16) & 1u);
    return (unsigned short)(u >> 16);
}
__device__ __forceinline__ float bf16_to_f32(unsigned short h) {
    return __uint_as_float(((unsigned)h) << 16);
}

// async global->LDS, 16B per lane; LDS dest = wave-uniform base + lane*16
__device__ __forceinline__ void gl_lds16(const unsigned short* g, unsigned short* l) {
    __builtin_amdgcn_global_load_lds(
        (const __attribute__((address_space(1))) void*)g,
        (__attribute__((address_space(3))) void*)l,
        16, 0, 0);
}

// ---------------- CSR build ----------------
__global__ void csr_count(const int* __restrict__ ei, int* __restrict__ counts, int E) {
    int e = blockIdx.x * 256 + threadIdx.x;
    if (e < E) atomicAdd(&counts[ei[E + e]], 1);
}

__global__ void csr_scan(const int* __restrict__ counts, int* __restrict__ rowptr,
                         int* __restrict__ cursor, int N, int E) {
    __shared__ int sh[1024];
    int t = threadIdx.x;
    int chunk = (N + 1023) / 1024;
    int lo = t * chunk, hi = lo + chunk; if (hi > N) hi = N; if (lo > N) lo = N;
    int run = 0;
    for (int i = lo; i < hi; i++) { rowptr[i] = run; run += counts[i]; }
    sh[t] = run;
    __syncthreads();
    for (int d = 1; d < 1024; d <<= 1) {
        int v = (t >= d) ? sh[t - d] : 0;
        __syncthreads();
        sh[t] += v;
        __syncthreads();
    }
    int off = sh[t] - run;
    for (int i = lo; i < hi; i++) {
        int v = rowptr[i] + off;
        rowptr[i] = v; cursor[i] = v;
    }
    if (t == 0) rowptr[N] = E;
}

__global__ void csr_fill(const int* __restrict__ ei, int* __restrict__ cursor,
                         int* __restrict__ colsrc, int E) {
    int e = blockIdx.x * 256 + threadIdx.x;
    if (e < E) {
        int s = ei[e], d = ei[E + e];
        int p = atomicAdd(&cursor[d], 1);
        colsrc[p] = s;
    }
}

// ---------------- weight prep: W[l][k][n] fp32 -> Wt_hi/lo[mat][n][k] bf16 ----------------
__global__ void wprep(const float* __restrict__ W1, const float* __restrict__ W2,
                      unsigned short* __restrict__ Whi, unsigned short* __restrict__ Wlo) {
    int id = blockIdx.x * 256 + threadIdx.x;   // mat*65536 + k4*512 + n
    int mat = id >> 16;
    int k4 = (id >> 9) & 127;
    int n = id & 511;
    const float* W = (mat & 1) ? W2 : W1;
    const float* base = W + (size_t)(mat >> 1) * DIM * DIM;
    u16x4 h, l;
#pragma unroll
    for (int j = 0; j < 4; j++) {
        float v = base[(size_t)(k4 * 4 + j) * DIM + n];
        unsigned short hh = f32_to_bf16(v);
        h[j] = hh;
        l[j] = f32_to_bf16(v - bf16_to_f32(hh));
    }
    size_t o = ((size_t)mat * DIM + n) * DIM + k4 * 4;
    *reinterpret_cast<u16x4*>(Whi + o) = h;
    *reinterpret_cast<u16x4*>(Wlo + o) = l;
}

// ---------------- aggregation -> bf16 hi/lo planes (row-per-block) ----------------
// MODE 0: T = identity (layer 0, H = x).  MODE 1: T(v) = relu(relu(v*a2+c2)*a3+c3)
// Plane writes are NON-TEMPORAL: pure streaming output, never re-read before the
// next GEMM streams it. Keeps H resident in the Infinity Cache for the gather.
template<int MODE>
__global__ void agg_kernel(const float* __restrict__ H,
                           const int* __restrict__ rowptr, const int* __restrict__ colsrc,
                           const float* __restrict__ pa2, const float* __restrict__ pc2,
                           const float* __restrict__ pa3, const float* __restrict__ pc3,
                           unsigned short* __restrict__ Phi, unsigned short* __restrict__ Plo,
                           int N) {
    int n = blockIdx.x;
    int c = threadIdx.x * 4;   // 128 threads * float4 = 512 cols
    f32x4 a2, c2, a3, c3;
    if (MODE) {
        a2 = *reinterpret_cast<const f32x4*>(pa2 + c);
        c2 = *reinterpret_cast<const f32x4*>(pc2 + c);
        a3 = *reinterpret_cast<const f32x4*>(pa3 + c);
        c3 = *reinterpret_cast<const f32x4*>(pc3 + c);
    }
    auto xf = [&](f32x4 v) -> f32x4 {
        if (MODE) {
#pragma unroll
            for (int j = 0; j < 4; j++) {
                float f = fmaxf(v[j] * a2[j] + c2[j], 0.f);
                v[j] = fmaxf(f * a3[j] + c3[j], 0.f);
            }
        }
        return v;
    };
    auto ld = [&](int r) -> f32x4 {
        return *reinterpret_cast<const f32x4*>(H + (size_t)r * DIM + c);
    };
    f32x4 acc = xf(ld(n));
    int e0 = rowptr[n], e1 = rowptr[n + 1];
    int e = e0;
    for (; e + 4 <= e1; e += 4) {
        int s0 = colsrc[e], s1 = colsrc[e + 1], s2 = colsrc[e + 2], s3 = colsrc[e + 3];
        f32x4 v0 = ld(s0);
        f32x4 v1 = ld(s1);
        f32x4 v2 = ld(s2);
        f32x4 v3 = ld(s3);
        acc += xf(v0); acc += xf(v1); acc += xf(v2); acc += xf(v3);
    }
    for (; e < e1; e++) acc += xf(ld(colsrc[e]));
    u16x4 h, l;
#pragma unroll
    for (int j = 0; j < 4; j++) {
        unsigned short hh = f32_to_bf16(acc[j]);
        h[j] = hh;
        l[j] = f32_to_bf16(acc[j] - bf16_to_f32(hh));
    }
    __builtin_nontemporal_store(h, reinterpret_cast<u16x4*>(Phi + (size_t)n * DIM + c));
    __builtin_nontemporal_store(l, reinterpret_cast<u16x4*>(Plo + (size_t)n * DIM + c));
}

// ---------------- convert: planes = split(relu(Y*a + c)) ----------------
// y1 is dead after this pass -> non-temporal load; plane writes non-temporal.
__global__ void convert_kernel(const float* __restrict__ Y,
                               const float* __restrict__ pa, const float* __restrict__ pc,
                               unsigned short* __restrict__ Phi, unsigned short* __restrict__ Plo,
                               int total8) {
    int i = blockIdx.x * blockDim.x + threadIdx.x;
    int stride = gridDim.x * blockDim.x;
    for (; i < total8; i += stride) {
        int cb = (i & 63) * 8;
        f32x4 v0 = __builtin_nontemporal_load(reinterpret_cast<const f32x4*>(Y + (size_t)i * 8));
        f32x4 v1 = __builtin_nontemporal_load(reinterpret_cast<const f32x4*>(Y + (size_t)i * 8 + 4));
        f32x4 a0 = *reinterpret_cast<const f32x4*>(pa + cb);
        f32x4 a1 = *reinterpret_cast<const f32x4*>(pa + cb + 4);
        f32x4 c0 = *reinterpret_cast<const f32x4*>(pc + cb);
        f32x4 c1 = *reinterpret_cast<const f32x4*>(pc + cb + 4);
        u16x8 h, l;
#pragma unroll
        for (int j = 0; j < 4; j++) {
            float f = fmaxf(v0[j] * a0[j] + c0[j], 0.f);
            unsigned short hh = f32_to_bf16(f);
            h[j] = hh;
            l[j] = f32_to_bf16(f - bf16_to_f32(hh));
        }
#pragma unroll
        for (int j = 0; j < 4; j++) {
            float f = fmaxf(v1[j] * a1[j] + c1[j], 0.f);
            unsigned short hh = f32_to_bf16(f);
            h[4 + j] = hh;
            l[4 + j] = f32_to_bf16(f - bf16_to_f32(hh));
        }
        __builtin_nontemporal_store(h, reinterpret_cast<u16x8*>(Phi + (size_t)i * 8));
        __builtin_nontemporal_store(l, reinterpret_cast<u16x8*>(Plo + (size_t)i * 8));
    }
}

// ---------------- GEMM: Y = A @ W + bias from bf16 hi/lo planes, + column stats ----------
// NTY=1: Y store non-temporal (y1: read once by convert, then dead).
// NTY=0: Y cached (Yout: re-read by ustats and the next layer's gather).
template<int NTY>
__global__ __launch_bounds__(256, 2)
void gemm_kernel(const unsigned short* __restrict__ Ahi,
                 const unsigned short* __restrict__ Alo,
                 const unsigned short* __restrict__ Bhi,
                 const unsigned short* __restrict__ Blo,
                 const float* __restrict__ bias,
                 float* __restrict__ Y,
                 float* __restrict__ ssum, float* __restrict__ ssq,
                 int M) {
    __shared__ unsigned short lds[4 * GBM * GBK];   // 64 KB
    unsigned short* sAhi = lds;
    unsigned short* sAlo = lds + GBM * GBK;
    unsigned short* sBhi = lds + 2 * GBM * GBK;
    unsigned short* sBlo = lds + 3 * GBM * GBK;

    const int tid = threadIdx.x;
    const int lane = tid & 63;
    const int wave = tid >> 6;
    const int wm = wave >> 1, wn = wave & 1;

    // bijective swizzle: b -> (g = m-panel, j = n-block), g%8 == b%8 (same XCD)
    const int b = blockIdx.x;
    const int xcd = b & 7;
    const int slot = b >> 3;
    const int g = (slot >> 2) * 8 + xcd;
    const int j = slot & 3;
    const int m0 = g * GBM;
    const int n0 = j * GBN;

    const int lrow = lane >> 3;        // 0..7 within 8-row group
    const int lkc = (lane & 7) * 8;    // element col offset (8 bf16 = 16B)

    f32x4 acc[4][4];
#pragma unroll
    for (int i = 0; i < 4; i++)
#pragma unroll
        for (int jj = 0; jj < 4; jj++) acc[i][jj] = (f32x4){0.f, 0.f, 0.f, 0.f};

    for (int kt = 0; kt < DIM; kt += GBK) {
        __syncthreads();
#pragma unroll
        for (int i = 0; i < 4; i++) {
            int r = wave * 8 + i * 32 + lrow;                 // tile row 0..127
            int ldso = wave * 512 + i * 2048;                 // wave-uniform LDS elem offset
            size_t ga = (size_t)(m0 + r) * DIM + kt + lkc;
            size_t gb = (size_t)(n0 + r) * DIM + kt + lkc;
            gl_lds16(Ahi + ga, sAhi + ldso);
            gl_lds16(Alo + ga, sAlo + ldso);
            gl_lds16(Bhi + gb, sBhi + ldso);
            gl_lds16(Blo + gb, sBlo + ldso);
        }
        __syncthreads();
#pragma unroll
        for (int ks = 0; ks < 2; ks++) {
            const int kk = ks * 32 + (lane >> 4) * 8;
            const int ar = wm * 64 + (lane & 15);
            const int br = wn * 64 + (lane & 15);
            bf16x8 ah[4], al_[4], bh[4], bl[4];
#pragma unroll
            for (int f = 0; f < 4; f++) {
                ah[f]  = *reinterpret_cast<const bf16x8*>(&sAhi[(ar + f * 16) * GBK + kk]);
                al_[f] = *reinterpret_cast<const bf16x8*>(&sAlo[(ar + f * 16) * GBK + kk]);
                bh[f]  = *reinterpret_cast<const bf16x8*>(&sBhi[(br + f * 16) * GBK + kk]);
                bl[f]  = *reinterpret_cast<const bf16x8*>(&sBlo[(br + f * 16) * GBK + kk]);
            }
#pragma unroll
            for (int mf = 0; mf < 4; mf++)
#pragma unroll
                for (int nf = 0; nf < 4; nf++) {
                    acc[mf][nf] = __builtin_amdgcn_mfma_f32_16x16x32_bf16(al_[mf], bh[nf], acc[mf][nf], 0, 0, 0);
                    acc[mf][nf] = __builtin_amdgcn_mfma_f32_16x16x32_bf16(ah[mf], bl[nf], acc[mf][nf], 0, 0, 0);
                    acc[mf][nf] = __builtin_amdgcn_mfma_f32_16x16x32_bf16(ah[mf], bh[nf], acc[mf][nf], 0, 0, 0);
                }
        }
    }

    // epilogue: bias add, store, column stats
    const int ln16 = lane & 15;
    const int lg = lane >> 4;
#pragma unroll
    for (int nf = 0; nf < 4; nf++) {
        int col = n0 + wn * 64 + nf * 16 + ln16;
        float bv = bias[col];
        float s = 0.f, q = 0.f;
#pragma unroll
        for (int mf = 0; mf < 4; mf++) {
#pragma unroll
            for (int r = 0; r < 4; r++) {
                int row = m0 + wm * 64 + mf * 16 + lg * 4 + r;
                if (row < M) {
                    float v = acc[mf][nf][r] + bv;
                    if (NTY)
                        __builtin_nontemporal_store(v, &Y[(size_t)row * DIM + col]);
                    else
                        Y[(size_t)row * DIM + col] = v;
                    s += v; q += v * v;
                }
            }
        }
        s += __shfl_xor(s, 16);
        s += __shfl_xor(s, 32);
        q += __shfl_xor(q, 16);
        q += __shfl_xor(q, 32);
        if (lg == 0) {
            atomicAdd(&ssum[col], s);
            atomicAdd(&ssq[col], q);
        }
    }
}

// ---------------- column stats of u = relu?(Y*a + c) ----------------
template<int RELU>
__global__ void ustats_kernel(const float* __restrict__ Y,
                              const float* __restrict__ pa, const float* __restrict__ pc,
                              float* __restrict__ ssum, float* __restrict__ ssq,
                              int M, int chunk) {
    int d = blockIdx.x * blockDim.x + threadIdx.x;
    int r0 = blockIdx.y * chunk;
    int r1 = r0 + chunk; if (r1 > M) r1 = M;
    float a = pa[d], c = pc[d];
    float s = 0.f, q = 0.f;
    for (int r = r0; r < r1; r++) {
        float v = Y[(size_t)r * DIM + d] * a + c;
        if (RELU) v = fmaxf(v, 0.f);
        s += v; q += v * v;
    }
    atomicAdd(&ssum[d], s);
    atomicAdd(&ssq[d], q);
}

// ---------------- BN params: a = g*rsqrt(var+eps), c = beta - mean*a ----------------
__global__ void params_kernel(const float* __restrict__ ssum, const float* __restrict__ ssq,
                              const float* __restrict__ g, const float* __restrict__ b,
                              float* __restrict__ pa, float* __restrict__ pc, float invN) {
    int d = threadIdx.x + blockIdx.x * blockDim.x;
    float m = ssum[d] * invN;
    float var = ssq[d] * invN - m * m;
    var = fmaxf(var, 0.f);
    float s = rsqrtf(var + 1e-5f);
    float a = g[d] * s;
    pa[d] = a;
    pc[d] = b[d] - m * a;
}

// ---------------- final in-place: out = (out*a2+c2)*a3+c3 ----------------
__global__ void finalize_kernel(float* __restrict__ Y,
                                const float* __restrict__ pa2, const float* __restrict__ pc2,
                                const float* __restrict__ pa3, const float* __restrict__ pc3,
                                int total4) {
    int i = blockIdx.x * blockDim.x + threadIdx.x;
    int stride = gridDim.x * blockDim.x;
    for (; i < total4; i += stride) {
        int c = (i & 127) * 4;
        f32x4 v = *reinterpret_cast<f32x4*>(Y + (size_t)i * 4);
#pragma unroll
        for (int j = 0; j < 4; j++) {
            float f = v[j] * pa2[c + j] + pc2[c + j];
            v[j] = f * pa3[c + j] + pc3[c + j];
        }
        *reinterpret_cast<f32x4*>(Y + (size_t)i * 4) = v;
    }
}

extern "C" void kernel_launch(void* const* d_in, const int* in_sizes, int n_in,
                              void* d_out, int out_size, void* d_ws, size_t ws_size,
                              hipStream_t stream) {
    const float* x   = (const float*)d_in[0];
    const int*   ei  = (const int*)d_in[1];
    const float* W1  = (const float*)d_in[2];
    const float* b1  = (const float*)d_in[3];
    const float* g1  = (const float*)d_in[4];
    const float* be1 = (const float*)d_in[5];
    const float* W2  = (const float*)d_in[6];
    const float* b2  = (const float*)d_in[7];
    const float* g2  = (const float*)d_in[8];
    const float* be2 = (const float*)d_in[9];
    const float* ng  = (const float*)d_in[10];
    const float* nb  = (const float*)d_in[11];

    const int N = in_sizes[0] / DIM;
    const int E = in_sizes[1] / 2;

    char* ws = (char*)d_ws;
    size_t off = 0;
    auto alloc = [&](size_t bytes) -> void* {
        void* p = ws + off;
        off += (bytes + 255) & ~(size_t)255;
        return p;
    };
    unsigned short* Phi = (unsigned short*)alloc((size_t)N * DIM * 2);
    unsigned short* Plo = (unsigned short*)alloc((size_t)N * DIM * 2);
    float* y1 = (float*)alloc((size_t)N * DIM * 4);
    unsigned short* Whi = (unsigned short*)alloc(6ull * DIM * DIM * 2);
    unsigned short* Wlo = (unsigned short*)alloc(6ull * DIM * DIM * 2);
    int* rowptr = (int*)alloc((size_t)(N + 1) * 4);
    int* counts = (int*)alloc((size_t)N * 4);
    int* cursor = (int*)alloc((size_t)N * 4);
    int* colsrc = (int*)alloc((size_t)E * 4);
    float* stats = (float*)alloc(9ull * 1024 * 4);
    float* prm = (float*)alloc(6ull * DIM * 4);

    float* Yout = (float*)d_out;
    float* pa1 = prm,         *pc1 = prm + DIM;
    float* pa2 = prm + 2*DIM, *pc2 = prm + 3*DIM;
    float* pa3 = prm + 4*DIM, *pc3 = prm + 5*DIM;

    hipMemsetAsync(counts, 0, (size_t)N * 4, stream);
    hipMemsetAsync(stats, 0, 9ull * 1024 * 4, stream);

    wprep<<<1536, 256, 0, stream>>>(W1, W2, Whi, Wlo);
    csr_count<<<(E + 255) / 256, 256, 0, stream>>>(ei, counts, E);
    csr_scan<<<1, 1024, 0, stream>>>(counts, rowptr, cursor, N, E);
    csr_fill<<<(E + 255) / 256, 256, 0, stream>>>(ei, cursor, colsrc, E);

    const float invN = 1.0f / (float)N;
    const int Gm = ((N + GBM - 1) / GBM + 7) & ~7;
    const int gemm_blocks = Gm * 4;
    const int uchunk = (N + 199) / 200;
    const int total8 = N * DIM / 8;

    for (int l = 0; l < NLAYERS; l++) {
        float* st1 = stats + (size_t)l * 3 * 1024;
        float* st2 = st1 + 1024;
        float* st3 = st2 + 1024;
        if (l == 0)
            agg_kernel<0><<<N, 128, 0, stream>>>(x, rowptr, colsrc,
                                                 nullptr, nullptr, nullptr, nullptr,
                                                 Phi, Plo, N);
        else
            agg_kernel<1><<<N, 128, 0, stream>>>(Yout, rowptr, colsrc,
                                                 pa2, pc2, pa3, pc3, Phi, Plo, N);
        gemm_kernel<1><<<gemm_blocks, 256, 0, stream>>>(Phi, Plo,
            Whi + (size_t)(l * 2) * DIM * DIM, Wlo + (size_t)(l * 2) * DIM * DIM,
            b1 + l * DIM, y1, st1, st1 + 512, N);
        params_kernel<<<1, 512, 0, stream>>>(st1, st1 + 512, g1 + l * DIM, be1 + l * DIM,
                                             pa1, pc1, invN);
        convert_kernel<<<2048, 256, 0, stream>>>(y1, pa1, pc1, Phi, Plo, total8);
        gemm_kernel<0><<<gemm_blocks, 256, 0, stream>>>(Phi, Plo,
            Whi + (size_t)(l * 2 + 1) * DIM * DIM, Wlo + (size_t)(l * 2 + 1) * DIM * DIM,
            b2 + l * DIM, Yout, st2, st2 + 512, N);
        params_kernel<<<1, 512, 0, stream>>>(st2, st2 + 512, g2 + l * DIM, be2 + l * DIM,
                                             pa2, pc2, invN);
        if (l < NLAYERS - 1)
            ustats_kernel<1><<<dim3(2, 200), 256, 0, stream>>>(Yout, pa2, pc2,
                                                               st3, st3 + 512, N, uchunk);
        else
            ustats_kernel<0><<<dim3(2, 200), 256, 0, stream>>>(Yout, pa2, pc2,
                                                               st3, st3 + 512, N, uchunk);
        params_kernel<<<1, 512, 0, stream>>>(st3, st3 + 512, ng + l * DIM, nb + l * DIM,
                                             pa3, pc3, invN);
    }
    finalize_kernel<<<2048, 256, 0, stream>>>(Yout, pa2, pc2, pa3, pc3, N * DIM / 4);
}

// Round 8
// 2005.400 us; speedup vs baseline: 1.1108x; 1.1108x over previous
//
#include <hip/hip_runtime.h>
#include <cstdint>
#include <cstddef>

#define DIM 512
#define NLAYERS 3
#define GBM 128
#define GBN 128
#define GBK 64

typedef float f32x4 __attribute__((ext_vector_type(4)));
typedef short bf16x8 __attribute__((ext_vector_type(8)));
typedef unsigned short u16x4 __attribute__((ext_vector_type(4)));
typedef unsigned short u16x8 __attribute__((ext_vector_type(8)));

__device__ __forceinline__ unsigned short f32_to_bf16(float f) {
    unsigned u = __float_as_uint(f);
    u += 0x7fffu + ((u >> 16) & 1u);
    return (unsigned short)(u >> 16);
}
__device__ __forceinline__ float bf16_to_f32(unsigned short h) {
    return __uint_as_float(((unsigned)h) << 16);
}

// async global->LDS, 16B per lane; LDS dest = wave-uniform base + lane*16
__device__ __forceinline__ void gl_lds16(const unsigned short* g, unsigned short* l) {
    __builtin_amdgcn_global_load_lds(
        (const __attribute__((address_space(1))) void*)g,
        (__attribute__((address_space(3))) void*)l,
        16, 0, 0);
}

// ---------------- CSR build ----------------
__global__ void csr_count(const int* __restrict__ ei, int* __restrict__ counts, int E) {
    int e = blockIdx.x * 256 + threadIdx.x;
    if (e < E) atomicAdd(&counts[ei[E + e]], 1);
}

__global__ void csr_scan(const int* __restrict__ counts, int* __restrict__ rowptr,
                         int* __restrict__ cursor, int N, int E) {
    __shared__ int sh[1024];
    int t = threadIdx.x;
    int chunk = (N + 1023) / 1024;
    int lo = t * chunk, hi = lo + chunk; if (hi > N) hi = N; if (lo > N) lo = N;
    int run = 0;
    for (int i = lo; i < hi; i++) { rowptr[i] = run; run += counts[i]; }
    sh[t] = run;
    __syncthreads();
    for (int d = 1; d < 1024; d <<= 1) {
        int v = (t >= d) ? sh[t - d] : 0;
        __syncthreads();
        sh[t] += v;
        __syncthreads();
    }
    int off = sh[t] - run;
    for (int i = lo; i < hi; i++) {
        int v = rowptr[i] + off;
        rowptr[i] = v; cursor[i] = v;
    }
    if (t == 0) rowptr[N] = E;
}

__global__ void csr_fill(const int* __restrict__ ei, int* __restrict__ cursor,
                         int* __restrict__ colsrc, int E) {
    int e = blockIdx.x * 256 + threadIdx.x;
    if (e < E) {
        int s = ei[e], d = ei[E + e];
        int p = atomicAdd(&cursor[d], 1);
        colsrc[p] = s;
    }
}

// ---------------- weight prep: W[l][k][n] fp32 -> Wt_hi/lo[mat][n][k] bf16 ----------------
__global__ void wprep(const float* __restrict__ W1, const float* __restrict__ W2,
                      unsigned short* __restrict__ Whi, unsigned short* __restrict__ Wlo) {
    int id = blockIdx.x * 256 + threadIdx.x;   // mat*65536 + k4*512 + n
    int mat = id >> 16;
    int k4 = (id >> 9) & 127;
    int n = id & 511;
    const float* W = (mat & 1) ? W2 : W1;
    const float* base = W + (size_t)(mat >> 1) * DIM * DIM;
    u16x4 h, l;
#pragma unroll
    for (int j = 0; j < 4; j++) {
        float v = base[(size_t)(k4 * 4 + j) * DIM + n];
        unsigned short hh = f32_to_bf16(v);
        h[j] = hh;
        l[j] = f32_to_bf16(v - bf16_to_f32(hh));
    }
    size_t o = ((size_t)mat * DIM + n) * DIM + k4 * 4;
    *reinterpret_cast<u16x4*>(Whi + o) = h;
    *reinterpret_cast<u16x4*>(Wlo + o) = l;
}

// ---------------- layer-0 aggregation (fp32 x gather) -> z bf16 hi/lo planes -------------
__global__ void agg_kernel(const float* __restrict__ H,
                           const int* __restrict__ rowptr, const int* __restrict__ colsrc,
                           unsigned short* __restrict__ Phi, unsigned short* __restrict__ Plo,
                           int N) {
    int n = blockIdx.x;
    int c = threadIdx.x * 4;   // 128 threads * float4 = 512 cols
    auto ld = [&](int r) -> f32x4 {
        return *reinterpret_cast<const f32x4*>(H + (size_t)r * DIM + c);
    };
    f32x4 acc = ld(n);
    int e0 = rowptr[n], e1 = rowptr[n + 1];
    int e = e0;
    for (; e + 4 <= e1; e += 4) {
        int s0 = colsrc[e], s1 = colsrc[e + 1], s2 = colsrc[e + 2], s3 = colsrc[e + 3];
        f32x4 v0 = ld(s0);
        f32x4 v1 = ld(s1);
        f32x4 v2 = ld(s2);
        f32x4 v3 = ld(s3);
        acc += v0; acc += v1; acc += v2; acc += v3;
    }
    for (; e < e1; e++) acc += ld(colsrc[e]);
    u16x4 h, l;
#pragma unroll
    for (int j = 0; j < 4; j++) {
        unsigned short hh = f32_to_bf16(acc[j]);
        h[j] = hh;
        l[j] = f32_to_bf16(acc[j] - bf16_to_f32(hh));
    }
    __builtin_nontemporal_store(h, reinterpret_cast<u16x4*>(Phi + (size_t)n * DIM + c));
    __builtin_nontemporal_store(l, reinterpret_cast<u16x4*>(Plo + (size_t)n * DIM + c));
}

// ---------------- layer>=1 aggregation: gather bf16 u, T(u) = relu(u*a3+c3) --------------
// Halved gather footprint (51 MB): each XCD's structural full-coverage fetch drops 2x.
__global__ void agg_u(const unsigned short* __restrict__ U,
                      const int* __restrict__ rowptr, const int* __restrict__ colsrc,
                      const float* __restrict__ pa3, const float* __restrict__ pc3,
                      unsigned short* __restrict__ Phi, unsigned short* __restrict__ Plo,
                      int N) {
    int n = blockIdx.x;
    int c = threadIdx.x * 4;   // 128 threads * 4 bf16 = 512 cols
    f32x4 a3 = *reinterpret_cast<const f32x4*>(pa3 + c);
    f32x4 c3 = *reinterpret_cast<const f32x4*>(pc3 + c);
    auto ldT = [&](int r) -> f32x4 {
        u16x4 u = *reinterpret_cast<const u16x4*>(U + (size_t)r * DIM + c);
        f32x4 v;
#pragma unroll
        for (int j = 0; j < 4; j++)
            v[j] = fmaxf(bf16_to_f32(u[j]) * a3[j] + c3[j], 0.f);
        return v;
    };
    f32x4 acc = ldT(n);
    int e0 = rowptr[n], e1 = rowptr[n + 1];
    int e = e0;
    for (; e + 4 <= e1; e += 4) {
        int s0 = colsrc[e], s1 = colsrc[e + 1], s2 = colsrc[e + 2], s3 = colsrc[e + 3];
        f32x4 v0 = ldT(s0);
        f32x4 v1 = ldT(s1);
        f32x4 v2 = ldT(s2);
        f32x4 v3 = ldT(s3);
        acc += v0; acc += v1; acc += v2; acc += v3;
    }
    for (; e < e1; e++) acc += ldT(colsrc[e]);
    u16x4 h, l;
#pragma unroll
    for (int j = 0; j < 4; j++) {
        unsigned short hh = f32_to_bf16(acc[j]);
        h[j] = hh;
        l[j] = f32_to_bf16(acc[j] - bf16_to_f32(hh));
    }
    __builtin_nontemporal_store(h, reinterpret_cast<u16x4*>(Phi + (size_t)n * DIM + c));
    __builtin_nontemporal_store(l, reinterpret_cast<u16x4*>(Plo + (size_t)n * DIM + c));
}

// ---------------- convert: planes = split(relu(Y*a + c)) ----------------
__global__ void convert_kernel(const float* __restrict__ Y,
                               const float* __restrict__ pa, const float* __restrict__ pc,
                               unsigned short* __restrict__ Phi, unsigned short* __restrict__ Plo,
                               int total8) {
    int i = blockIdx.x * blockDim.x + threadIdx.x;
    int stride = gridDim.x * blockDim.x;
    for (; i < total8; i += stride) {
        int cb = (i & 63) * 8;
        f32x4 v0 = __builtin_nontemporal_load(reinterpret_cast<const f32x4*>(Y + (size_t)i * 8));
        f32x4 v1 = __builtin_nontemporal_load(reinterpret_cast<const f32x4*>(Y + (size_t)i * 8 + 4));
        f32x4 a0 = *reinterpret_cast<const f32x4*>(pa + cb);
        f32x4 a1 = *reinterpret_cast<const f32x4*>(pa + cb + 4);
        f32x4 c0 = *reinterpret_cast<const f32x4*>(pc + cb);
        f32x4 c1 = *reinterpret_cast<const f32x4*>(pc + cb + 4);
        u16x8 h, l;
#pragma unroll
        for (int j = 0; j < 4; j++) {
            float f = fmaxf(v0[j] * a0[j] + c0[j], 0.f);
            unsigned short hh = f32_to_bf16(f);
            h[j] = hh;
            l[j] = f32_to_bf16(f - bf16_to_f32(hh));
        }
#pragma unroll
        for (int j = 0; j < 4; j++) {
            float f = fmaxf(v1[j] * a1[j] + c1[j], 0.f);
            unsigned short hh = f32_to_bf16(f);
            h[4 + j] = hh;
            l[4 + j] = f32_to_bf16(f - bf16_to_f32(hh));
        }
        __builtin_nontemporal_store(h, reinterpret_cast<u16x8*>(Phi + (size_t)i * 8));
        __builtin_nontemporal_store(l, reinterpret_cast<u16x8*>(Plo + (size_t)i * 8));
    }
}

// ---------------- GEMM: Y = A @ W + bias from bf16 hi/lo planes, + column stats ----------
template<int NTY>
__global__ __launch_bounds__(256, 2)
void gemm_kernel(const unsigned short* __restrict__ Ahi,
                 const unsigned short* __restrict__ Alo,
                 const unsigned short* __restrict__ Bhi,
                 const unsigned short* __restrict__ Blo,
                 const float* __restrict__ bias,
                 float* __restrict__ Y,
                 float* __restrict__ ssum, float* __restrict__ ssq,
                 int M) {
    __shared__ unsigned short lds[4 * GBM * GBK];   // 64 KB
    unsigned short* sAhi = lds;
    unsigned short* sAlo = lds + GBM * GBK;
    unsigned short* sBhi = lds + 2 * GBM * GBK;
    unsigned short* sBlo = lds + 3 * GBM * GBK;

    const int tid = threadIdx.x;
    const int lane = tid & 63;
    const int wave = tid >> 6;
    const int wm = wave >> 1, wn = wave & 1;

    // bijective swizzle: b -> (g = m-panel, j = n-block), g%8 == b%8 (same XCD)
    const int b = blockIdx.x;
    const int xcd = b & 7;
    const int slot = b >> 3;
    const int g = (slot >> 2) * 8 + xcd;
    const int j = slot & 3;
    const int m0 = g * GBM;
    const int n0 = j * GBN;

    const int lrow = lane >> 3;        // 0..7 within 8-row group
    const int lkc = (lane & 7) * 8;    // element col offset (8 bf16 = 16B)

    f32x4 acc[4][4];
#pragma unroll
    for (int i = 0; i < 4; i++)
#pragma unroll
        for (int jj = 0; jj < 4; jj++) acc[i][jj] = (f32x4){0.f, 0.f, 0.f, 0.f};

    for (int kt = 0; kt < DIM; kt += GBK) {
        __syncthreads();
#pragma unroll
        for (int i = 0; i < 4; i++) {
            int r = wave * 8 + i * 32 + lrow;                 // tile row 0..127
            int ldso = wave * 512 + i * 2048;                 // wave-uniform LDS elem offset
            size_t ga = (size_t)(m0 + r) * DIM + kt + lkc;
            size_t gb = (size_t)(n0 + r) * DIM + kt + lkc;
            gl_lds16(Ahi + ga, sAhi + ldso);
            gl_lds16(Alo + ga, sAlo + ldso);
            gl_lds16(Bhi + gb, sBhi + ldso);
            gl_lds16(Blo + gb, sBlo + ldso);
        }
        __syncthreads();
#pragma unroll
        for (int ks = 0; ks < 2; ks++) {
            const int kk = ks * 32 + (lane >> 4) * 8;
            const int ar = wm * 64 + (lane & 15);
            const int br = wn * 64 + (lane & 15);
            bf16x8 ah[4], al_[4], bh[4], bl[4];
#pragma unroll
            for (int f = 0; f < 4; f++) {
                ah[f]  = *reinterpret_cast<const bf16x8*>(&sAhi[(ar + f * 16) * GBK + kk]);
                al_[f] = *reinterpret_cast<const bf16x8*>(&sAlo[(ar + f * 16) * GBK + kk]);
                bh[f]  = *reinterpret_cast<const bf16x8*>(&sBhi[(br + f * 16) * GBK + kk]);
                bl[f]  = *reinterpret_cast<const bf16x8*>(&sBlo[(br + f * 16) * GBK + kk]);
            }
#pragma unroll
            for (int mf = 0; mf < 4; mf++)
#pragma unroll
                for (int nf = 0; nf < 4; nf++) {
                    acc[mf][nf] = __builtin_amdgcn_mfma_f32_16x16x32_bf16(al_[mf], bh[nf], acc[mf][nf], 0, 0, 0);
                    acc[mf][nf] = __builtin_amdgcn_mfma_f32_16x16x32_bf16(ah[mf], bl[nf], acc[mf][nf], 0, 0, 0);
                    acc[mf][nf] = __builtin_amdgcn_mfma_f32_16x16x32_bf16(ah[mf], bh[nf], acc[mf][nf], 0, 0, 0);
                }
        }
    }

    // epilogue: bias add, store, column stats
    const int ln16 = lane & 15;
    const int lg = lane >> 4;
#pragma unroll
    for (int nf = 0; nf < 4; nf++) {
        int col = n0 + wn * 64 + nf * 16 + ln16;
        float bv = bias[col];
        float s = 0.f, q = 0.f;
#pragma unroll
        for (int mf = 0; mf < 4; mf++) {
#pragma unroll
            for (int r = 0; r < 4; r++) {
                int row = m0 + wm * 64 + mf * 16 + lg * 4 + r;
                if (row < M) {
                    float v = acc[mf][nf][r] + bv;
                    if (NTY)
                        __builtin_nontemporal_store(v, &Y[(size_t)row * DIM + col]);
                    else
                        Y[(size_t)row * DIM + col] = v;
                    s += v; q += v * v;
                }
            }
        }
        s += __shfl_xor(s, 16);
        s += __shfl_xor(s, 32);
        q += __shfl_xor(q, 16);
        q += __shfl_xor(q, 32);
        if (lg == 0) {
            atomicAdd(&ssum[col], s);
            atomicAdd(&ssq[col], q);
        }
    }
}

// ---------------- column stats of u = relu?(Y*a + c); optionally store u as bf16 ----------
template<int RELU, int STORE>
__global__ void ustats_kernel(const float* __restrict__ Y,
                              const float* __restrict__ pa, const float* __restrict__ pc,
                              float* __restrict__ ssum, float* __restrict__ ssq,
                              unsigned short* __restrict__ U,
                              int M, int chunk) {
    int d = blockIdx.x * blockDim.x + threadIdx.x;
    int r0 = blockIdx.y * chunk;
    int r1 = r0 + chunk; if (r1 > M) r1 = M;
    float a = pa[d], c = pc[d];
    float s = 0.f, q = 0.f;
    for (int r = r0; r < r1; r++) {
        float v = Y[(size_t)r * DIM + d] * a + c;
        if (RELU) v = fmaxf(v, 0.f);
        s += v; q += v * v;
        if (STORE) U[(size_t)r * DIM + d] = f32_to_bf16(v);
    }
    atomicAdd(&ssum[d], s);
    atomicAdd(&ssq[d], q);
}

// ---------------- BN params: a = g*rsqrt(var+eps), c = beta - mean*a ----------------
__global__ void params_kernel(const float* __restrict__ ssum, const float* __restrict__ ssq,
                              const float* __restrict__ g, const float* __restrict__ b,
                              float* __restrict__ pa, float* __restrict__ pc, float invN) {
    int d = threadIdx.x + blockIdx.x * blockDim.x;
    float m = ssum[d] * invN;
    float var = ssq[d] * invN - m * m;
    var = fmaxf(var, 0.f);
    float s = rsqrtf(var + 1e-5f);
    float a = g[d] * s;
    pa[d] = a;
    pc[d] = b[d] - m * a;
}

// ---------------- final in-place: out = (out*a2+c2)*a3+c3 ----------------
__global__ void finalize_kernel(float* __restrict__ Y,
                                const float* __restrict__ pa2, const float* __restrict__ pc2,
                                const float* __restrict__ pa3, const float* __restrict__ pc3,
                                int total4) {
    int i = blockIdx.x * blockDim.x + threadIdx.x;
    int stride = gridDim.x * blockDim.x;
    for (; i < total4; i += stride) {
        int c = (i & 127) * 4;
        f32x4 v = *reinterpret_cast<f32x4*>(Y + (size_t)i * 4);
#pragma unroll
        for (int j = 0; j < 4; j++) {
            float f = v[j] * pa2[c + j] + pc2[c + j];
            v[j] = f * pa3[c + j] + pc3[c + j];
        }
        *reinterpret_cast<f32x4*>(Y + (size_t)i * 4) = v;
    }
}

extern "C" void kernel_launch(void* const* d_in, const int* in_sizes, int n_in,
                              void* d_out, int out_size, void* d_ws, size_t ws_size,
                              hipStream_t stream) {
    const float* x   = (const float*)d_in[0];
    const int*   ei  = (const int*)d_in[1];
    const float* W1  = (const float*)d_in[2];
    const float* b1  = (const float*)d_in[3];
    const float* g1  = (const float*)d_in[4];
    const float* be1 = (const float*)d_in[5];
    const float* W2  = (const float*)d_in[6];
    const float* b2  = (const float*)d_in[7];
    const float* g2  = (const float*)d_in[8];
    const float* be2 = (const float*)d_in[9];
    const float* ng  = (const float*)d_in[10];
    const float* nb  = (const float*)d_in[11];

    const int N = in_sizes[0] / DIM;
    const int E = in_sizes[1] / 2;

    char* ws = (char*)d_ws;
    size_t off = 0;
    auto alloc = [&](size_t bytes) -> void* {
        void* p = ws + off;
        off += (bytes + 255) & ~(size_t)255;
        return p;
    };
    unsigned short* Phi = (unsigned short*)alloc((size_t)N * DIM * 2);
    unsigned short* Plo = (unsigned short*)alloc((size_t)N * DIM * 2);
    float* y1 = (float*)alloc((size_t)N * DIM * 4);
    unsigned short* Whi = (unsigned short*)alloc(6ull * DIM * DIM * 2);
    unsigned short* Wlo = (unsigned short*)alloc(6ull * DIM * DIM * 2);
    int* rowptr = (int*)alloc((size_t)(N + 1) * 4);
    int* counts = (int*)alloc((size_t)N * 4);
    int* cursor = (int*)alloc((size_t)N * 4);
    int* colsrc = (int*)alloc((size_t)E * 4);
    float* stats = (float*)alloc(9ull * 1024 * 4);
    float* prm = (float*)alloc(6ull * DIM * 4);

    // U (bf16 u-activations, 51 MB) aliases y1: y1 is dead after convert_kernel(l),
    // U is written by ustats(l) (after convert) and read by agg_u(l+1) (before the
    // next gemm1 rewrites y1). Lifetimes are disjoint.
    unsigned short* U = (unsigned short*)y1;

    float* Yout = (float*)d_out;
    float* pa1 = prm,         *pc1 = prm + DIM;
    float* pa2 = prm + 2*DIM, *pc2 = prm + 3*DIM;
    float* pa3 = prm + 4*DIM, *pc3 = prm + 5*DIM;

    hipMemsetAsync(counts, 0, (size_t)N * 4, stream);
    hipMemsetAsync(stats, 0, 9ull * 1024 * 4, stream);

    wprep<<<1536, 256, 0, stream>>>(W1, W2, Whi, Wlo);
    csr_count<<<(E + 255) / 256, 256, 0, stream>>>(ei, counts, E);
    csr_scan<<<1, 1024, 0, stream>>>(counts, rowptr, cursor, N, E);
    csr_fill<<<(E + 255) / 256, 256, 0, stream>>>(ei, cursor, colsrc, E);

    const float invN = 1.0f / (float)N;
    const int Gm = ((N + GBM - 1) / GBM + 7) & ~7;
    const int gemm_blocks = Gm * 4;
    const int uchunk = (N + 199) / 200;
    const int total8 = N * DIM / 8;

    for (int l = 0; l < NLAYERS; l++) {
        float* st1 = stats + (size_t)l * 3 * 1024;
        float* st2 = st1 + 1024;
        float* st3 = st2 + 1024;
        if (l == 0)
            agg_kernel<<<N, 128, 0, stream>>>(x, rowptr, colsrc, Phi, Plo, N);
        else
            agg_u<<<N, 128, 0, stream>>>(U, rowptr, colsrc, pa3, pc3, Phi, Plo, N);
        gemm_kernel<1><<<gemm_blocks, 256, 0, stream>>>(Phi, Plo,
            Whi + (size_t)(l * 2) * DIM * DIM, Wlo + (size_t)(l * 2) * DIM * DIM,
            b1 + l * DIM, y1, st1, st1 + 512, N);
        params_kernel<<<1, 512, 0, stream>>>(st1, st1 + 512, g1 + l * DIM, be1 + l * DIM,
                                             pa1, pc1, invN);
        convert_kernel<<<2048, 256, 0, stream>>>(y1, pa1, pc1, Phi, Plo, total8);
        gemm_kernel<0><<<gemm_blocks, 256, 0, stream>>>(Phi, Plo,
            Whi + (size_t)(l * 2 + 1) * DIM * DIM, Wlo + (size_t)(l * 2 + 1) * DIM * DIM,
            b2 + l * DIM, Yout, st2, st2 + 512, N);
        params_kernel<<<1, 512, 0, stream>>>(st2, st2 + 512, g2 + l * DIM, be2 + l * DIM,
                                             pa2, pc2, invN);
        if (l < NLAYERS - 1)
            ustats_kernel<1, 1><<<dim3(2, 200), 256, 0, stream>>>(Yout, pa2, pc2,
                                                                  st3, st3 + 512, U, N, uchunk);
        else
            ustats_kernel<0, 0><<<dim3(2, 200), 256, 0, stream>>>(Yout, pa2, pc2,
                                                                  st3, st3 + 512, U, N, uchunk);
        params_kernel<<<1, 512, 0, stream>>>(st3, st3 + 512, ng + l * DIM, nb + l * DIM,
                                             pa3, pc3, invN);
    }
    finalize_kernel<<<2048, 256, 0, stream>>>(Yout, pa2, pc2, pa3, pc3, N * DIM / 4);
}

// Round 9
// 1963.980 us; speedup vs baseline: 1.1342x; 1.0211x over previous
//
#include <hip/hip_runtime.h>
#include <cstdint>
#include <cstddef>

#define DIM 512
#define NLAYERS 3
#define GBM 128
#define GBN 128
#define GBK 64

typedef float f32x4 __attribute__((ext_vector_type(4)));
typedef short bf16x8 __attribute__((ext_vector_type(8)));
typedef unsigned short u16x4 __attribute__((ext_vector_type(4)));
typedef unsigned short u16x8 __attribute__((ext_vector_type(8)));

__device__ __forceinline__ unsigned short f32_to_bf16(float f) {
    unsigned u = __float_as_uint(f);
    u += 0x7fffu + ((u >> 16) & 1u);
    return (unsigned short)(u >> 16);
}
__device__ __forceinline__ float bf16_to_f32(unsigned short h) {
    return __uint_as_float(((unsigned)h) << 16);
}

// async global->LDS, 16B per lane; LDS dest = wave-uniform base + lane*16 (linear).
// Swizzled layouts are achieved by pre-swizzling the per-lane GLOBAL source address.
__device__ __forceinline__ void gl_lds16(const unsigned short* g, unsigned short* l) {
    __builtin_amdgcn_global_load_lds(
        (const __attribute__((address_space(1))) void*)g,
        (__attribute__((address_space(3))) void*)l,
        16, 0, 0);
}

// ---------------- CSR build ----------------
__global__ void csr_count(const int* __restrict__ ei, int* __restrict__ counts, int E) {
    int e = blockIdx.x * 256 + threadIdx.x;
    if (e < E) atomicAdd(&counts[ei[E + e]], 1);
}

__global__ void csr_scan(const int* __restrict__ counts, int* __restrict__ rowptr,
                         int* __restrict__ cursor, int N, int E) {
    __shared__ int sh[1024];
    int t = threadIdx.x;
    int chunk = (N + 1023) / 1024;
    int lo = t * chunk, hi = lo + chunk; if (hi > N) hi = N; if (lo > N) lo = N;
    int run = 0;
    for (int i = lo; i < hi; i++) { rowptr[i] = run; run += counts[i]; }
    sh[t] = run;
    __syncthreads();
    for (int d = 1; d < 1024; d <<= 1) {
        int v = (t >= d) ? sh[t - d] : 0;
        __syncthreads();
        sh[t] += v;
        __syncthreads();
    }
    int off = sh[t] - run;
    for (int i = lo; i < hi; i++) {
        int v = rowptr[i] + off;
        rowptr[i] = v; cursor[i] = v;
    }
    if (t == 0) rowptr[N] = E;
}

__global__ void csr_fill(const int* __restrict__ ei, int* __restrict__ cursor,
                         int* __restrict__ colsrc, int E) {
    int e = blockIdx.x * 256 + threadIdx.x;
    if (e < E) {
        int s = ei[e], d = ei[E + e];
        int p = atomicAdd(&cursor[d], 1);
        colsrc[p] = s;
    }
}

// ---------------- weight prep: W[l][k][n] fp32 -> Wt_hi/lo[mat][n][k] bf16 ----------------
__global__ void wprep(const float* __restrict__ W1, const float* __restrict__ W2,
                      unsigned short* __restrict__ Whi, unsigned short* __restrict__ Wlo) {
    int id = blockIdx.x * 256 + threadIdx.x;   // mat*65536 + k4*512 + n
    int mat = id >> 16;
    int k4 = (id >> 9) & 127;
    int n = id & 511;
    const float* W = (mat & 1) ? W2 : W1;
    const float* base = W + (size_t)(mat >> 1) * DIM * DIM;
    u16x4 h, l;
#pragma unroll
    for (int j = 0; j < 4; j++) {
        float v = base[(size_t)(k4 * 4 + j) * DIM + n];
        unsigned short hh = f32_to_bf16(v);
        h[j] = hh;
        l[j] = f32_to_bf16(v - bf16_to_f32(hh));
    }
    size_t o = ((size_t)mat * DIM + n) * DIM + k4 * 4;
    *reinterpret_cast<u16x4*>(Whi + o) = h;
    *reinterpret_cast<u16x4*>(Wlo + o) = l;
}

// ---------------- layer-0 aggregation (fp32 x gather) -> z bf16 hi/lo planes -------------
__global__ void agg_kernel(const float* __restrict__ H,
                           const int* __restrict__ rowptr, const int* __restrict__ colsrc,
                           unsigned short* __restrict__ Phi, unsigned short* __restrict__ Plo,
                           int N) {
    int n = blockIdx.x;
    int c = threadIdx.x * 4;   // 128 threads * float4 = 512 cols
    auto ld = [&](int r) -> f32x4 {
        return *reinterpret_cast<const f32x4*>(H + (size_t)r * DIM + c);
    };
    f32x4 acc = ld(n);
    int e0 = rowptr[n], e1 = rowptr[n + 1];
    int e = e0;
    for (; e + 4 <= e1; e += 4) {
        int s0 = colsrc[e], s1 = colsrc[e + 1], s2 = colsrc[e + 2], s3 = colsrc[e + 3];
        f32x4 v0 = ld(s0);
        f32x4 v1 = ld(s1);
        f32x4 v2 = ld(s2);
        f32x4 v3 = ld(s3);
        acc += v0; acc += v1; acc += v2; acc += v3;
    }
    for (; e < e1; e++) acc += ld(colsrc[e]);
    u16x4 h, l;
#pragma unroll
    for (int j = 0; j < 4; j++) {
        unsigned short hh = f32_to_bf16(acc[j]);
        h[j] = hh;
        l[j] = f32_to_bf16(acc[j] - bf16_to_f32(hh));
    }
    __builtin_nontemporal_store(h, reinterpret_cast<u16x4*>(Phi + (size_t)n * DIM + c));
    __builtin_nontemporal_store(l, reinterpret_cast<u16x4*>(Plo + (size_t)n * DIM + c));
}

// ---------------- layer>=1 aggregation: gather bf16 u, T(u) = relu(u*a3+c3) --------------
__global__ void agg_u(const unsigned short* __restrict__ U,
                      const int* __restrict__ rowptr, const int* __restrict__ colsrc,
                      const float* __restrict__ pa3, const float* __restrict__ pc3,
                      unsigned short* __restrict__ Phi, unsigned short* __restrict__ Plo,
                      int N) {
    int n = blockIdx.x;
    int c = threadIdx.x * 4;   // 128 threads * 4 bf16 = 512 cols
    f32x4 a3 = *reinterpret_cast<const f32x4*>(pa3 + c);
    f32x4 c3 = *reinterpret_cast<const f32x4*>(pc3 + c);
    auto ldT = [&](int r) -> f32x4 {
        u16x4 u = *reinterpret_cast<const u16x4*>(U + (size_t)r * DIM + c);
        f32x4 v;
#pragma unroll
        for (int j = 0; j < 4; j++)
            v[j] = fmaxf(bf16_to_f32(u[j]) * a3[j] + c3[j], 0.f);
        return v;
    };
    f32x4 acc = ldT(n);
    int e0 = rowptr[n], e1 = rowptr[n + 1];
    int e = e0;
    for (; e + 4 <= e1; e += 4) {
        int s0 = colsrc[e], s1 = colsrc[e + 1], s2 = colsrc[e + 2], s3 = colsrc[e + 3];
        f32x4 v0 = ldT(s0);
        f32x4 v1 = ldT(s1);
        f32x4 v2 = ldT(s2);
        f32x4 v3 = ldT(s3);
        acc += v0; acc += v1; acc += v2; acc += v3;
    }
    for (; e < e1; e++) acc += ldT(colsrc[e]);
    u16x4 h, l;
#pragma unroll
    for (int j = 0; j < 4; j++) {
        unsigned short hh = f32_to_bf16(acc[j]);
        h[j] = hh;
        l[j] = f32_to_bf16(acc[j] - bf16_to_f32(hh));
    }
    __builtin_nontemporal_store(h, reinterpret_cast<u16x4*>(Phi + (size_t)n * DIM + c));
    __builtin_nontemporal_store(l, reinterpret_cast<u16x4*>(Plo + (size_t)n * DIM + c));
}

// ---------------- convert: planes = split(relu(Y*a + c)) ----------------
__global__ void convert_kernel(const float* __restrict__ Y,
                               const float* __restrict__ pa, const float* __restrict__ pc,
                               unsigned short* __restrict__ Phi, unsigned short* __restrict__ Plo,
                               int total8) {
    int i = blockIdx.x * blockDim.x + threadIdx.x;
    int stride = gridDim.x * blockDim.x;
    for (; i < total8; i += stride) {
        int cb = (i & 63) * 8;
        f32x4 v0 = __builtin_nontemporal_load(reinterpret_cast<const f32x4*>(Y + (size_t)i * 8));
        f32x4 v1 = __builtin_nontemporal_load(reinterpret_cast<const f32x4*>(Y + (size_t)i * 8 + 4));
        f32x4 a0 = *reinterpret_cast<const f32x4*>(pa + cb);
        f32x4 a1 = *reinterpret_cast<const f32x4*>(pa + cb + 4);
        f32x4 c0 = *reinterpret_cast<const f32x4*>(pc + cb);
        f32x4 c1 = *reinterpret_cast<const f32x4*>(pc + cb + 4);
        u16x8 h, l;
#pragma unroll
        for (int j = 0; j < 4; j++) {
            float f = fmaxf(v0[j] * a0[j] + c0[j], 0.f);
            unsigned short hh = f32_to_bf16(f);
            h[j] = hh;
            l[j] = f32_to_bf16(f - bf16_to_f32(hh));
        }
#pragma unroll
        for (int j = 0; j < 4; j++) {
            float f = fmaxf(v1[j] * a1[j] + c1[j], 0.f);
            unsigned short hh = f32_to_bf16(f);
            h[4 + j] = hh;
            l[4 + j] = f32_to_bf16(f - bf16_to_f32(hh));
        }
        __builtin_nontemporal_store(h, reinterpret_cast<u16x8*>(Phi + (size_t)i * 8));
        __builtin_nontemporal_store(l, reinterpret_cast<u16x8*>(Plo + (size_t)i * 8));
    }
}

// ---------------- GEMM: Y = A @ W + bias from bf16 hi/lo planes, + column stats ----------
// LDS tiles are [128 rows][64 elems] bf16 (row stride 128 B = 32 banks). Without swizzle,
// the fragment read (16 lanes -> 16 rows, same col chunk) is a 16-way bank conflict.
// Fix (T2, rule #21): keep gl_lds dest LINEAR, pre-swizzle the per-lane GLOBAL source
// column chunk (chunk ^= row&7), and XOR the same pattern into the ds_read address.
template<int NTY>
__global__ __launch_bounds__(256, 2)
void gemm_kernel(const unsigned short* __restrict__ Ahi,
                 const unsigned short* __restrict__ Alo,
                 const unsigned short* __restrict__ Bhi,
                 const unsigned short* __restrict__ Blo,
                 const float* __restrict__ bias,
                 float* __restrict__ Y,
                 float* __restrict__ ssum, float* __restrict__ ssq,
                 int M) {
    __shared__ unsigned short lds[4 * GBM * GBK];   // 64 KB
    unsigned short* sAhi = lds;
    unsigned short* sAlo = lds + GBM * GBK;
    unsigned short* sBhi = lds + 2 * GBM * GBK;
    unsigned short* sBlo = lds + 3 * GBM * GBK;

    const int tid = threadIdx.x;
    const int lane = tid & 63;
    const int wave = tid >> 6;
    const int wm = wave >> 1, wn = wave & 1;

    // bijective swizzle: b -> (g = m-panel, j = n-block), g%8 == b%8 (same XCD)
    const int b = blockIdx.x;
    const int xcd = b & 7;
    const int slot = b >> 3;
    const int g = (slot >> 2) * 8 + xcd;
    const int j = slot & 3;
    const int m0 = g * GBM;
    const int n0 = j * GBN;

    const int lrow = lane >> 3;                         // 0..7: row within 8-row group
    const int lkc = ((lane & 7) ^ lrow) * 8;            // PRE-SWIZZLED source col chunk

    f32x4 acc[4][4];
#pragma unroll
    for (int i = 0; i < 4; i++)
#pragma unroll
        for (int jj = 0; jj < 4; jj++) acc[i][jj] = (f32x4){0.f, 0.f, 0.f, 0.f};

    for (int kt = 0; kt < DIM; kt += GBK) {
        __syncthreads();
#pragma unroll
        for (int i = 0; i < 4; i++) {
            int r = wave * 8 + i * 32 + lrow;                 // tile row 0..127
            int ldso = wave * 512 + i * 2048;                 // wave-uniform LDS elem offset
            size_t ga = (size_t)(m0 + r) * DIM + kt + lkc;
            size_t gb = (size_t)(n0 + r) * DIM + kt + lkc;
            gl_lds16(Ahi + ga, sAhi + ldso);
            gl_lds16(Alo + ga, sAlo + ldso);
            gl_lds16(Bhi + gb, sBhi + ldso);
            gl_lds16(Blo + gb, sBlo + ldso);
        }
        __syncthreads();
#pragma unroll
        for (int ks = 0; ks < 2; ks++) {
            const int kk = ks * 32 + (lane >> 4) * 8;
            const int ar = wm * 64 + (lane & 15);
            const int br = wn * 64 + (lane & 15);
            bf16x8 ah[4], al_[4], bh[4], bl[4];
#pragma unroll
            for (int f = 0; f < 4; f++) {
                int ra = ar + f * 16, rb = br + f * 16;
                int oa = ra * GBK + (kk ^ ((ra & 7) << 3));   // swizzled ds_read addr
                int ob = rb * GBK + (kk ^ ((rb & 7) << 3));
                ah[f]  = *reinterpret_cast<const bf16x8*>(&sAhi[oa]);
                al_[f] = *reinterpret_cast<const bf16x8*>(&sAlo[oa]);
                bh[f]  = *reinterpret_cast<const bf16x8*>(&sBhi[ob]);
                bl[f]  = *reinterpret_cast<const bf16x8*>(&sBlo[ob]);
            }
#pragma unroll
            for (int mf = 0; mf < 4; mf++)
#pragma unroll
                for (int nf = 0; nf < 4; nf++) {
                    acc[mf][nf] = __builtin_amdgcn_mfma_f32_16x16x32_bf16(al_[mf], bh[nf], acc[mf][nf], 0, 0, 0);
                    acc[mf][nf] = __builtin_amdgcn_mfma_f32_16x16x32_bf16(ah[mf], bl[nf], acc[mf][nf], 0, 0, 0);
                    acc[mf][nf] = __builtin_amdgcn_mfma_f32_16x16x32_bf16(ah[mf], bh[nf], acc[mf][nf], 0, 0, 0);
                }
        }
    }

    // epilogue: bias add, store, column stats
    const int ln16 = lane & 15;
    const int lg = lane >> 4;
#pragma unroll
    for (int nf = 0; nf < 4; nf++) {
        int col = n0 + wn * 64 + nf * 16 + ln16;
        float bv = bias[col];
        float s = 0.f, q = 0.f;
#pragma unroll
        for (int mf = 0; mf < 4; mf++) {
#pragma unroll
            for (int r = 0; r < 4; r++) {
                int row = m0 + wm * 64 + mf * 16 + lg * 4 + r;
                if (row < M) {
                    float v = acc[mf][nf][r] + bv;
                    if (NTY)
                        __builtin_nontemporal_store(v, &Y[(size_t)row * DIM + col]);
                    else
                        Y[(size_t)row * DIM + col] = v;
                    s += v; q += v * v;
                }
            }
        }
        s += __shfl_xor(s, 16);
        s += __shfl_xor(s, 32);
        q += __shfl_xor(q, 16);
        q += __shfl_xor(q, 32);
        if (lg == 0) {
            atomicAdd(&ssum[col], s);
            atomicAdd(&ssq[col], q);
        }
    }
}

// ---------------- column stats of u = relu?(Y*a + c); optionally store u as bf16 ----------
template<int RELU, int STORE>
__global__ void ustats_kernel(const float* __restrict__ Y,
                              const float* __restrict__ pa, const float* __restrict__ pc,
                              float* __restrict__ ssum, float* __restrict__ ssq,
                              unsigned short* __restrict__ U,
                              int M, int chunk) {
    int d = blockIdx.x * blockDim.x + threadIdx.x;
    int r0 = blockIdx.y * chunk;
    int r1 = r0 + chunk; if (r1 > M) r1 = M;
    float a = pa[d], c = pc[d];
    float s = 0.f, q = 0.f;
    for (int r = r0; r < r1; r++) {
        float v = Y[(size_t)r * DIM + d] * a + c;
        if (RELU) v = fmaxf(v, 0.f);
        s += v; q += v * v;
        if (STORE) U[(size_t)r * DIM + d] = f32_to_bf16(v);
    }
    atomicAdd(&ssum[d], s);
    atomicAdd(&ssq[d], q);
}

// ---------------- BN params: a = g*rsqrt(var+eps), c = beta - mean*a ----------------
__global__ void params_kernel(const float* __restrict__ ssum, const float* __restrict__ ssq,
                              const float* __restrict__ g, const float* __restrict__ b,
                              float* __restrict__ pa, float* __restrict__ pc, float invN) {
    int d = threadIdx.x + blockIdx.x * blockDim.x;
    float m = ssum[d] * invN;
    float var = ssq[d] * invN - m * m;
    var = fmaxf(var, 0.f);
    float s = rsqrtf(var + 1e-5f);
    float a = g[d] * s;
    pa[d] = a;
    pc[d] = b[d] - m * a;
}

// ---------------- final in-place: out = (out*a2+c2)*a3+c3 ----------------
__global__ void finalize_kernel(float* __restrict__ Y,
                                const float* __restrict__ pa2, const float* __restrict__ pc2,
                                const float* __restrict__ pa3, const float* __restrict__ pc3,
                                int total4) {
    int i = blockIdx.x * blockDim.x + threadIdx.x;
    int stride = gridDim.x * blockDim.x;
    for (; i < total4; i += stride) {
        int c = (i & 127) * 4;
        f32x4 v = *reinterpret_cast<f32x4*>(Y + (size_t)i * 4);
#pragma unroll
        for (int j = 0; j < 4; j++) {
            float f = v[j] * pa2[c + j] + pc2[c + j];
            v[j] = f * pa3[c + j] + pc3[c + j];
        }
        *reinterpret_cast<f32x4*>(Y + (size_t)i * 4) = v;
    }
}

extern "C" void kernel_launch(void* const* d_in, const int* in_sizes, int n_in,
                              void* d_out, int out_size, void* d_ws, size_t ws_size,
                              hipStream_t stream) {
    const float* x   = (const float*)d_in[0];
    const int*   ei  = (const int*)d_in[1];
    const float* W1  = (const float*)d_in[2];
    const float* b1  = (const float*)d_in[3];
    const float* g1  = (const float*)d_in[4];
    const float* be1 = (const float*)d_in[5];
    const float* W2  = (const float*)d_in[6];
    const float* b2  = (const float*)d_in[7];
    const float* g2  = (const float*)d_in[8];
    const float* be2 = (const float*)d_in[9];
    const float* ng  = (const float*)d_in[10];
    const float* nb  = (const float*)d_in[11];

    const int N = in_sizes[0] / DIM;
    const int E = in_sizes[1] / 2;

    char* ws = (char*)d_ws;
    size_t off = 0;
    auto alloc = [&](size_t bytes) -> void* {
        void* p = ws + off;
        off += (bytes + 255) & ~(size_t)255;
        return p;
    };
    unsigned short* Phi = (unsigned short*)alloc((size_t)N * DIM * 2);
    unsigned short* Plo = (unsigned short*)alloc((size_t)N * DIM * 2);
    float* y1 = (float*)alloc((size_t)N * DIM * 4);
    unsigned short* Whi = (unsigned short*)alloc(6ull * DIM * DIM * 2);
    unsigned short* Wlo = (unsigned short*)alloc(6ull * DIM * DIM * 2);
    int* rowptr = (int*)alloc((size_t)(N + 1) * 4);
    int* counts = (int*)alloc((size_t)N * 4);
    int* cursor = (int*)alloc((size_t)N * 4);
    int* colsrc = (int*)alloc((size_t)E * 4);
    float* stats = (float*)alloc(9ull * 1024 * 4);
    float* prm = (float*)alloc(6ull * DIM * 4);

    // U (bf16 u-activations, 51 MB) aliases y1: y1 is dead after convert_kernel(l),
    // U is written by ustats(l) (after convert) and read by agg_u(l+1) (before the
    // next gemm1 rewrites y1). Lifetimes are disjoint.
    unsigned short* U = (unsigned short*)y1;

    float* Yout = (float*)d_out;
    float* pa1 = prm,         *pc1 = prm + DIM;
    float* pa2 = prm + 2*DIM, *pc2 = prm + 3*DIM;
    float* pa3 = prm + 4*DIM, *pc3 = prm + 5*DIM;

    hipMemsetAsync(counts, 0, (size_t)N * 4, stream);
    hipMemsetAsync(stats, 0, 9ull * 1024 * 4, stream);

    wprep<<<1536, 256, 0, stream>>>(W1, W2, Whi, Wlo);
    csr_count<<<(E + 255) / 256, 256, 0, stream>>>(ei, counts, E);
    csr_scan<<<1, 1024, 0, stream>>>(counts, rowptr, cursor, N, E);
    csr_fill<<<(E + 255) / 256, 256, 0, stream>>>(ei, cursor, colsrc, E);

    const float invN = 1.0f / (float)N;
    const int Gm = ((N + GBM - 1) / GBM + 7) & ~7;
    const int gemm_blocks = Gm * 4;
    const int uchunk = (N + 199) / 200;
    const int total8 = N * DIM / 8;

    for (int l = 0; l < NLAYERS; l++) {
        float* st1 = stats + (size_t)l * 3 * 1024;
        float* st2 = st1 + 1024;
        float* st3 = st2 + 1024;
        if (l == 0)
            agg_kernel<<<N, 128, 0, stream>>>(x, rowptr, colsrc, Phi, Plo, N);
        else
            agg_u<<<N, 128, 0, stream>>>(U, rowptr, colsrc, pa3, pc3, Phi, Plo, N);
        gemm_kernel<1><<<gemm_blocks, 256, 0, stream>>>(Phi, Plo,
            Whi + (size_t)(l * 2) * DIM * DIM, Wlo + (size_t)(l * 2) * DIM * DIM,
            b1 + l * DIM, y1, st1, st1 + 512, N);
        params_kernel<<<1, 512, 0, stream>>>(st1, st1 + 512, g1 + l * DIM, be1 + l * DIM,
                                             pa1, pc1, invN);
        convert_kernel<<<2048, 256, 0, stream>>>(y1, pa1, pc1, Phi, Plo, total8);
        gemm_kernel<0><<<gemm_blocks, 256, 0, stream>>>(Phi, Plo,
            Whi + (size_t)(l * 2 + 1) * DIM * DIM, Wlo + (size_t)(l * 2 + 1) * DIM * DIM,
            b2 + l * DIM, Yout, st2, st2 + 512, N);
        params_kernel<<<1, 512, 0, stream>>>(st2, st2 + 512, g2 + l * DIM, be2 + l * DIM,
                                             pa2, pc2, invN);
        if (l < NLAYERS - 1)
            ustats_kernel<1, 1><<<dim3(2, 200), 256, 0, stream>>>(Yout, pa2, pc2,
                                                                  st3, st3 + 512, U, N, uchunk);
        else
            ustats_kernel<0, 0><<<dim3(2, 200), 256, 0, stream>>>(Yout, pa2, pc2,
                                                                  st3, st3 + 512, U, N, uchunk);
        params_kernel<<<1, 512, 0, stream>>>(st3, st3 + 512, ng + l * DIM, nb + l * DIM,
                                             pa3, pc3, invN);
    }
    finalize_kernel<<<2048, 256, 0, stream>>>(Yout, pa2, pc2, pa3, pc3, N * DIM / 4);
}

// Round 10
// 1601.890 us; speedup vs baseline: 1.3906x; 1.2260x over previous
//
#include <hip/hip_runtime.h>
#include <cstdint>
#include <cstddef>

#define DIM 512
#define NLAYERS 3
#define GBM 128
#define GBN 128
#define GBK 64

typedef float f32x4 __attribute__((ext_vector_type(4)));
typedef short bf16x8 __attribute__((ext_vector_type(8)));
typedef unsigned short u16x4 __attribute__((ext_vector_type(4)));
typedef unsigned short u16x8 __attribute__((ext_vector_type(8)));

__device__ __forceinline__ unsigned short f32_to_bf16(float f) {
    unsigned u = __float_as_uint(f);
    u += 0x7fffu + ((u >> 16) & 1u);
    return (unsigned short)(u >> 16);
}
__device__ __forceinline__ float bf16_to_f32(unsigned short h) {
    return __uint_as_float(((unsigned)h) << 16);
}

// async global->LDS, 16B per lane; LDS dest = wave-uniform base + lane*16 (linear).
__device__ __forceinline__ void gl_lds16(const unsigned short* g, unsigned short* l) {
    __builtin_amdgcn_global_load_lds(
        (const __attribute__((address_space(1))) void*)g,
        (__attribute__((address_space(3))) void*)l,
        16, 0, 0);
}

// ---------------- CSR build ----------------
__global__ void csr_count(const int* __restrict__ ei, int* __restrict__ counts, int E) {
    int e = blockIdx.x * 256 + threadIdx.x;
    if (e < E) atomicAdd(&counts[ei[E + e]], 1);
}

__global__ void csr_scan(const int* __restrict__ counts, int* __restrict__ rowptr,
                         int* __restrict__ cursor, int N, int E) {
    __shared__ int sh[1024];
    int t = threadIdx.x;
    int chunk = (N + 1023) / 1024;
    int lo = t * chunk, hi = lo + chunk; if (hi > N) hi = N; if (lo > N) lo = N;
    int run = 0;
    for (int i = lo; i < hi; i++) { rowptr[i] = run; run += counts[i]; }
    sh[t] = run;
    __syncthreads();
    for (int d = 1; d < 1024; d <<= 1) {
        int v = (t >= d) ? sh[t - d] : 0;
        __syncthreads();
        sh[t] += v;
        __syncthreads();
    }
    int off = sh[t] - run;
    for (int i = lo; i < hi; i++) {
        int v = rowptr[i] + off;
        rowptr[i] = v; cursor[i] = v;
    }
    if (t == 0) rowptr[N] = E;
}

__global__ void csr_fill(const int* __restrict__ ei, int* __restrict__ cursor,
                         int* __restrict__ colsrc, int E) {
    int e = blockIdx.x * 256 + threadIdx.x;
    if (e < E) {
        int s = ei[e], d = ei[E + e];
        int p = atomicAdd(&cursor[d], 1);
        colsrc[p] = s;
    }
}

// ---------------- weight prep: W[l][k][n] fp32 -> Wt_hi/lo[mat][n][k] bf16 ----------------
__global__ void wprep(const float* __restrict__ W1, const float* __restrict__ W2,
                      unsigned short* __restrict__ Whi, unsigned short* __restrict__ Wlo) {
    int id = blockIdx.x * 256 + threadIdx.x;   // mat*65536 + k4*512 + n
    int mat = id >> 16;
    int k4 = (id >> 9) & 127;
    int n = id & 511;
    const float* W = (mat & 1) ? W2 : W1;
    const float* base = W + (size_t)(mat >> 1) * DIM * DIM;
    u16x4 h, l;
#pragma unroll
    for (int j = 0; j < 4; j++) {
        float v = base[(size_t)(k4 * 4 + j) * DIM + n];
        unsigned short hh = f32_to_bf16(v);
        h[j] = hh;
        l[j] = f32_to_bf16(v - bf16_to_f32(hh));
    }
    size_t o = ((size_t)mat * DIM + n) * DIM + k4 * 4;
    *reinterpret_cast<u16x4*>(Whi + o) = h;
    *reinterpret_cast<u16x4*>(Wlo + o) = l;
}

// ---------------- xprep: Xbf = bf16(x) (halves layer-0 gather footprint) ----------------
__global__ void xprep(const float* __restrict__ X, unsigned short* __restrict__ Xbf,
                      int total8) {
    int i = blockIdx.x * blockDim.x + threadIdx.x;
    int stride = gridDim.x * blockDim.x;
    for (; i < total8; i += stride) {
        f32x4 v0 = *reinterpret_cast<const f32x4*>(X + (size_t)i * 8);
        f32x4 v1 = *reinterpret_cast<const f32x4*>(X + (size_t)i * 8 + 4);
        u16x8 h;
#pragma unroll
        for (int j = 0; j < 4; j++) h[j] = f32_to_bf16(v0[j]);
#pragma unroll
        for (int j = 0; j < 4; j++) h[4 + j] = f32_to_bf16(v1[j]);
        __builtin_nontemporal_store(h, reinterpret_cast<u16x8*>(Xbf + (size_t)i * 8));
    }
}

// ---------------- aggregation over bf16 rows -> A-hi plane ----------------
// MODE 0: T = identity (layer 0, U = bf16(x)).  MODE 1: T(v) = relu(v*a3+c3)
template<int MODE>
__global__ void agg_b(const unsigned short* __restrict__ U,
                      const int* __restrict__ rowptr, const int* __restrict__ colsrc,
                      const float* __restrict__ pa3, const float* __restrict__ pc3,
                      unsigned short* __restrict__ Phi, int N) {
    int n = blockIdx.x;
    int c = threadIdx.x * 4;   // 128 threads * 4 bf16 = 512 cols
    f32x4 a3, c3;
    if (MODE) {
        a3 = *reinterpret_cast<const f32x4*>(pa3 + c);
        c3 = *reinterpret_cast<const f32x4*>(pc3 + c);
    }
    auto ldT = [&](int r) -> f32x4 {
        u16x4 u = *reinterpret_cast<const u16x4*>(U + (size_t)r * DIM + c);
        f32x4 v;
#pragma unroll
        for (int j = 0; j < 4; j++) {
            float f = bf16_to_f32(u[j]);
            v[j] = MODE ? fmaxf(f * a3[j] + c3[j], 0.f) : f;
        }
        return v;
    };
    f32x4 acc = ldT(n);
    int e0 = rowptr[n], e1 = rowptr[n + 1];
    int e = e0;
    for (; e + 4 <= e1; e += 4) {
        int s0 = colsrc[e], s1 = colsrc[e + 1], s2 = colsrc[e + 2], s3 = colsrc[e + 3];
        f32x4 v0 = ldT(s0);
        f32x4 v1 = ldT(s1);
        f32x4 v2 = ldT(s2);
        f32x4 v3 = ldT(s3);
        acc += v0; acc += v1; acc += v2; acc += v3;
    }
    for (; e < e1; e++) acc += ldT(colsrc[e]);
    u16x4 h;
#pragma unroll
    for (int j = 0; j < 4; j++) h[j] = f32_to_bf16(acc[j]);
    __builtin_nontemporal_store(h, reinterpret_cast<u16x4*>(Phi + (size_t)n * DIM + c));
}

// ---------------- convert: Phi = bf16(relu(Y*a + c)) ----------------
__global__ void convert_kernel(const float* __restrict__ Y,
                               const float* __restrict__ pa, const float* __restrict__ pc,
                               unsigned short* __restrict__ Phi, int total8) {
    int i = blockIdx.x * blockDim.x + threadIdx.x;
    int stride = gridDim.x * blockDim.x;
    for (; i < total8; i += stride) {
        int cb = (i & 63) * 8;
        f32x4 v0 = __builtin_nontemporal_load(reinterpret_cast<const f32x4*>(Y + (size_t)i * 8));
        f32x4 v1 = __builtin_nontemporal_load(reinterpret_cast<const f32x4*>(Y + (size_t)i * 8 + 4));
        f32x4 a0 = *reinterpret_cast<const f32x4*>(pa + cb);
        f32x4 a1 = *reinterpret_cast<const f32x4*>(pa + cb + 4);
        f32x4 c0 = *reinterpret_cast<const f32x4*>(pc + cb);
        f32x4 c1 = *reinterpret_cast<const f32x4*>(pc + cb + 4);
        u16x8 h;
#pragma unroll
        for (int j = 0; j < 4; j++)
            h[j] = f32_to_bf16(fmaxf(v0[j] * a0[j] + c0[j], 0.f));
#pragma unroll
        for (int j = 0; j < 4; j++)
            h[4 + j] = f32_to_bf16(fmaxf(v1[j] * a1[j] + c1[j], 0.f));
        __builtin_nontemporal_store(h, reinterpret_cast<u16x8*>(Phi + (size_t)i * 8));
    }
}

// ---------------- GEMM (2-pass): Y = Ahi @ (Whi + Wlo) + bias, + column stats ----------
// 48 KB LDS, 3 blocks/CU. A bf16-only; W keeps hi/lo planes for near-fp32 weights.
template<int NTY>
__global__ __launch_bounds__(256, 3)
void gemm_kernel(const unsigned short* __restrict__ Ahi,
                 const unsigned short* __restrict__ Bhi,
                 const unsigned short* __restrict__ Blo,
                 const float* __restrict__ bias,
                 float* __restrict__ Y,
                 float* __restrict__ ssum, float* __restrict__ ssq,
                 int M) {
    __shared__ unsigned short lds[3 * GBM * GBK];   // 48 KB
    unsigned short* sAhi = lds;
    unsigned short* sBhi = lds + GBM * GBK;
    unsigned short* sBlo = lds + 2 * GBM * GBK;

    const int tid = threadIdx.x;
    const int lane = tid & 63;
    const int wave = tid >> 6;
    const int wm = wave >> 1, wn = wave & 1;

    // bijective swizzle: b -> (g = m-panel, j = n-block), g%8 == b%8 (same XCD)
    const int b = blockIdx.x;
    const int xcd = b & 7;
    const int slot = b >> 3;
    const int g = (slot >> 2) * 8 + xcd;
    const int j = slot & 3;
    const int m0 = g * GBM;
    const int n0 = j * GBN;

    const int lrow = lane >> 3;                         // 0..7: row within 8-row group
    const int lkc = ((lane & 7) ^ lrow) * 8;            // pre-swizzled source col chunk

    f32x4 acc[4][4];
#pragma unroll
    for (int i = 0; i < 4; i++)
#pragma unroll
        for (int jj = 0; jj < 4; jj++) acc[i][jj] = (f32x4){0.f, 0.f, 0.f, 0.f};

    for (int kt = 0; kt < DIM; kt += GBK) {
        __syncthreads();
#pragma unroll
        for (int i = 0; i < 4; i++) {
            int r = wave * 8 + i * 32 + lrow;                 // tile row 0..127
            int ldso = wave * 512 + i * 2048;                 // wave-uniform LDS elem offset
            size_t ga = (size_t)(m0 + r) * DIM + kt + lkc;
            size_t gb = (size_t)(n0 + r) * DIM + kt + lkc;
            gl_lds16(Ahi + ga, sAhi + ldso);
            gl_lds16(Bhi + gb, sBhi + ldso);
            gl_lds16(Blo + gb, sBlo + ldso);
        }
        __syncthreads();
#pragma unroll
        for (int ks = 0; ks < 2; ks++) {
            const int kk = ks * 32 + (lane >> 4) * 8;
            const int ar = wm * 64 + (lane & 15);
            const int br = wn * 64 + (lane & 15);
            bf16x8 bh[4], bl[4];
#pragma unroll
            for (int f = 0; f < 4; f++) {
                int rb = br + f * 16;
                int ob = rb * GBK + (kk ^ ((rb & 7) << 3));
                bh[f] = *reinterpret_cast<const bf16x8*>(&sBhi[ob]);
                bl[f] = *reinterpret_cast<const bf16x8*>(&sBlo[ob]);
            }
#pragma unroll
            for (int mf = 0; mf < 4; mf++) {
                int ra = ar + mf * 16;
                int oa = ra * GBK + (kk ^ ((ra & 7) << 3));
                bf16x8 a = *reinterpret_cast<const bf16x8*>(&sAhi[oa]);
#pragma unroll
                for (int nf = 0; nf < 4; nf++) {
                    acc[mf][nf] = __builtin_amdgcn_mfma_f32_16x16x32_bf16(a, bl[nf], acc[mf][nf], 0, 0, 0);
                    acc[mf][nf] = __builtin_amdgcn_mfma_f32_16x16x32_bf16(a, bh[nf], acc[mf][nf], 0, 0, 0);
                }
            }
        }
    }

    // epilogue: bias add, store, column stats
    const int ln16 = lane & 15;
    const int lg = lane >> 4;
#pragma unroll
    for (int nf = 0; nf < 4; nf++) {
        int col = n0 + wn * 64 + nf * 16 + ln16;
        float bv = bias[col];
        float s = 0.f, q = 0.f;
#pragma unroll
        for (int mf = 0; mf < 4; mf++) {
#pragma unroll
            for (int r = 0; r < 4; r++) {
                int row = m0 + wm * 64 + mf * 16 + lg * 4 + r;
                if (row < M) {
                    float v = acc[mf][nf][r] + bv;
                    if (NTY)
                        __builtin_nontemporal_store(v, &Y[(size_t)row * DIM + col]);
                    else
                        Y[(size_t)row * DIM + col] = v;
                    s += v; q += v * v;
                }
            }
        }
        s += __shfl_xor(s, 16);
        s += __shfl_xor(s, 32);
        q += __shfl_xor(q, 16);
        q += __shfl_xor(q, 32);
        if (lg == 0) {
            atomicAdd(&ssum[col], s);
            atomicAdd(&ssq[col], q);
        }
    }
}

// ---------------- column stats of u = relu?(Y*a + c); optionally store u as bf16 ----------
template<int RELU, int STORE>
__global__ void ustats_kernel(const float* __restrict__ Y,
                              const float* __restrict__ pa, const float* __restrict__ pc,
                              float* __restrict__ ssum, float* __restrict__ ssq,
                              unsigned short* __restrict__ U,
                              int M, int chunk) {
    int d = blockIdx.x * blockDim.x + threadIdx.x;
    int r0 = blockIdx.y * chunk;
    int r1 = r0 + chunk; if (r1 > M) r1 = M;
    float a = pa[d], c = pc[d];
    float s = 0.f, q = 0.f;
    for (int r = r0; r < r1; r++) {
        float v = Y[(size_t)r * DIM + d] * a + c;
        if (RELU) v = fmaxf(v, 0.f);
        s += v; q += v * v;
        if (STORE) U[(size_t)r * DIM + d] = f32_to_bf16(v);
    }
    atomicAdd(&ssum[d], s);
    atomicAdd(&ssq[d], q);
}

// ---------------- BN params: a = g*rsqrt(var+eps), c = beta - mean*a ----------------
__global__ void params_kernel(const float* __restrict__ ssum, const float* __restrict__ ssq,
                              const float* __restrict__ g, const float* __restrict__ b,
                              float* __restrict__ pa, float* __restrict__ pc, float invN) {
    int d = threadIdx.x + blockIdx.x * blockDim.x;
    float m = ssum[d] * invN;
    float var = ssq[d] * invN - m * m;
    var = fmaxf(var, 0.f);
    float s = rsqrtf(var + 1e-5f);
    float a = g[d] * s;
    pa[d] = a;
    pc[d] = b[d] - m * a;
}

// ---------------- final in-place: out = (out*a2+c2)*a3+c3 ----------------
__global__ void finalize_kernel(float* __restrict__ Y,
                                const float* __restrict__ pa2, const float* __restrict__ pc2,
                                const float* __restrict__ pa3, const float* __restrict__ pc3,
                                int total4) {
    int i = blockIdx.x * blockDim.x + threadIdx.x;
    int stride = gridDim.x * blockDim.x;
    for (; i < total4; i += stride) {
        int c = (i & 127) * 4;
        f32x4 v = *reinterpret_cast<f32x4*>(Y + (size_t)i * 4);
#pragma unroll
        for (int j = 0; j < 4; j++) {
            float f = v[j] * pa2[c + j] + pc2[c + j];
            v[j] = f * pa3[c + j] + pc3[c + j];
        }
        *reinterpret_cast<f32x4*>(Y + (size_t)i * 4) = v;
    }
}

extern "C" void kernel_launch(void* const* d_in, const int* in_sizes, int n_in,
                              void* d_out, int out_size, void* d_ws, size_t ws_size,
                              hipStream_t stream) {
    const float* x   = (const float*)d_in[0];
    const int*   ei  = (const int*)d_in[1];
    const float* W1  = (const float*)d_in[2];
    const float* b1  = (const float*)d_in[3];
    const float* g1  = (const float*)d_in[4];
    const float* be1 = (const float*)d_in[5];
    const float* W2  = (const float*)d_in[6];
    const float* b2  = (const float*)d_in[7];
    const float* g2  = (const float*)d_in[8];
    const float* be2 = (const float*)d_in[9];
    const float* ng  = (const float*)d_in[10];
    const float* nb  = (const float*)d_in[11];

    const int N = in_sizes[0] / DIM;
    const int E = in_sizes[1] / 2;

    char* ws = (char*)d_ws;
    size_t off = 0;
    auto alloc = [&](size_t bytes) -> void* {
        void* p = ws + off;
        off += (bytes + 255) & ~(size_t)255;
        return p;
    };
    unsigned short* Phi = (unsigned short*)alloc((size_t)N * DIM * 2);
    unsigned short* Xbf = (unsigned short*)alloc((size_t)N * DIM * 2);
    float* y1 = (float*)alloc((size_t)N * DIM * 4);
    unsigned short* Whi = (unsigned short*)alloc(6ull * DIM * DIM * 2);
    unsigned short* Wlo = (unsigned short*)alloc(6ull * DIM * DIM * 2);
    int* rowptr = (int*)alloc((size_t)(N + 1) * 4);
    int* counts = (int*)alloc((size_t)N * 4);
    int* cursor = (int*)alloc((size_t)N * 4);
    int* colsrc = (int*)alloc((size_t)E * 4);
    float* stats = (float*)alloc(9ull * 1024 * 4);
    float* prm = (float*)alloc(6ull * DIM * 4);

    // U (bf16 u-activations, 51 MB) aliases y1: y1 dead after convert(l); U written by
    // ustats(l), read by agg_b(l+1) before gemm1 rewrites y1. Lifetimes disjoint.
    unsigned short* U = (unsigned short*)y1;

    float* Yout = (float*)d_out;
    float* pa1 = prm,         *pc1 = prm + DIM;
    float* pa2 = prm + 2*DIM, *pc2 = prm + 3*DIM;
    float* pa3 = prm + 4*DIM, *pc3 = prm + 5*DIM;

    hipMemsetAsync(counts, 0, (size_t)N * 4, stream);
    hipMemsetAsync(stats, 0, 9ull * 1024 * 4, stream);

    wprep<<<1536, 256, 0, stream>>>(W1, W2, Whi, Wlo);
    xprep<<<2048, 256, 0, stream>>>(x, Xbf, N * DIM / 8);
    csr_count<<<(E + 255) / 256, 256, 0, stream>>>(ei, counts, E);
    csr_scan<<<1, 1024, 0, stream>>>(counts, rowptr, cursor, N, E);
    csr_fill<<<(E + 255) / 256, 256, 0, stream>>>(ei, cursor, colsrc, E);

    const float invN = 1.0f / (float)N;
    const int Gm = ((N + GBM - 1) / GBM + 7) & ~7;
    const int gemm_blocks = Gm * 4;
    const int uchunk = (N + 199) / 200;
    const int total8 = N * DIM / 8;

    for (int l = 0; l < NLAYERS; l++) {
        float* st1 = stats + (size_t)l * 3 * 1024;
        float* st2 = st1 + 1024;
        float* st3 = st2 + 1024;
        if (l == 0)
            agg_b<0><<<N, 128, 0, stream>>>(Xbf, rowptr, colsrc, nullptr, nullptr, Phi, N);
        else
            agg_b<1><<<N, 128, 0, stream>>>(U, rowptr, colsrc, pa3, pc3, Phi, N);
        gemm_kernel<1><<<gemm_blocks, 256, 0, stream>>>(Phi,
            Whi + (size_t)(l * 2) * DIM * DIM, Wlo + (size_t)(l * 2) * DIM * DIM,
            b1 + l * DIM, y1, st1, st1 + 512, N);
        params_kernel<<<1, 512, 0, stream>>>(st1, st1 + 512, g1 + l * DIM, be1 + l * DIM,
                                             pa1, pc1, invN);
        convert_kernel<<<2048, 256, 0, stream>>>(y1, pa1, pc1, Phi, total8);
        gemm_kernel<0><<<gemm_blocks, 256, 0, stream>>>(Phi,
            Whi + (size_t)(l * 2 + 1) * DIM * DIM, Wlo + (size_t)(l * 2 + 1) * DIM * DIM,
            b2 + l * DIM, Yout, st2, st2 + 512, N);
        params_kernel<<<1, 512, 0, stream>>>(st2, st2 + 512, g2 + l * DIM, be2 + l * DIM,
                                             pa2, pc2, invN);
        if (l < NLAYERS - 1)
            ustats_kernel<1, 1><<<dim3(2, 200), 256, 0, stream>>>(Yout, pa2, pc2,
                                                                  st3, st3 + 512, U, N, uchunk);
        else
            ustats_kernel<0, 0><<<dim3(2, 200), 256, 0, stream>>>(Yout, pa2, pc2,
                                                                  st3, st3 + 512, U, N, uchunk);
        params_kernel<<<1, 512, 0, stream>>>(st3, st3 + 512, ng + l * DIM, nb + l * DIM,
                                             pa3, pc3, invN);
    }
    finalize_kernel<<<2048, 256, 0, stream>>>(Yout, pa2, pc2, pa3, pc3, N * DIM / 4);
}

// Round 11
// 1488.034 us; speedup vs baseline: 1.4970x; 1.0765x over previous
//
#include <hip/hip_runtime.h>
#include <cstdint>
#include <cstddef>

#define DIM 512
#define NLAYERS 3
#define GBM 128
#define GBN 128
#define GBK 64

typedef float f32x4 __attribute__((ext_vector_type(4)));
typedef short bf16x8 __attribute__((ext_vector_type(8)));
typedef unsigned short u16x4 __attribute__((ext_vector_type(4)));
typedef unsigned short u16x8 __attribute__((ext_vector_type(8)));

__device__ __forceinline__ unsigned short f32_to_bf16(float f) {
    unsigned u = __float_as_uint(f);
    u += 0x7fffu + ((u >> 16) & 1u);
    return (unsigned short)(u >> 16);
}
__device__ __forceinline__ float bf16_to_f32(unsigned short h) {
    return __uint_as_float(((unsigned)h) << 16);
}

// async global->LDS, 16B per lane; LDS dest = wave-uniform base + lane*16 (linear).
__device__ __forceinline__ void gl_lds16(const unsigned short* g, unsigned short* l) {
    __builtin_amdgcn_global_load_lds(
        (const __attribute__((address_space(1))) void*)g,
        (__attribute__((address_space(3))) void*)l,
        16, 0, 0);
}

// ---------------- CSR build ----------------
__global__ void csr_count(const int* __restrict__ ei, int* __restrict__ counts, int E) {
    int e = blockIdx.x * 256 + threadIdx.x;
    if (e < E) atomicAdd(&counts[ei[E + e]], 1);
}

// device-wide exclusive scan, 3 passes (all full-grid; replaces 143 us single-block scan)
__global__ void scan1(const int* __restrict__ counts, int* __restrict__ rowptr,
                      int* __restrict__ bsum, int N) {
    __shared__ int sh[256];
    int t = threadIdx.x;
    int i = blockIdx.x * 256 + t;
    int v = (i < N) ? counts[i] : 0;
    sh[t] = v;
    __syncthreads();
    for (int d = 1; d < 256; d <<= 1) {
        int u = (t >= d) ? sh[t - d] : 0;
        __syncthreads();
        sh[t] += u;
        __syncthreads();
    }
    if (i < N) rowptr[i] = sh[t] - v;        // exclusive within block
    if (t == 255) bsum[blockIdx.x] = sh[255]; // block total
}

__global__ void scan2(int* __restrict__ bsum, int NB) {
    __shared__ int sh[256];
    int t = threadIdx.x;
    int v = (t < NB) ? bsum[t] : 0;
    sh[t] = v;
    __syncthreads();
    for (int d = 1; d < 256; d <<= 1) {
        int u = (t >= d) ? sh[t - d] : 0;
        __syncthreads();
        sh[t] += u;
        __syncthreads();
    }
    if (t < NB) bsum[t] = sh[t] - v;          // exclusive block offsets
}

__global__ void scan3(const int* __restrict__ bsum, int* __restrict__ rowptr,
                      int* __restrict__ cursor, int N, int E) {
    int i = blockIdx.x * 256 + threadIdx.x;
    if (i < N) {
        int v = rowptr[i] + bsum[blockIdx.x];
        rowptr[i] = v;
        cursor[i] = v;
    }
    if (blockIdx.x == 0 && threadIdx.x == 0) rowptr[N] = E;
}

__global__ void csr_fill(const int* __restrict__ ei, int* __restrict__ cursor,
                         int* __restrict__ colsrc, int E) {
    int e = blockIdx.x * 256 + threadIdx.x;
    if (e < E) {
        int s = ei[e], d = ei[E + e];
        int p = atomicAdd(&cursor[d], 1);
        colsrc[p] = s;
    }
}

// ---------------- weight prep: W[l][k][n] fp32 -> Wt_hi/lo[mat][n][k] bf16 ----------------
__global__ void wprep(const float* __restrict__ W1, const float* __restrict__ W2,
                      unsigned short* __restrict__ Whi, unsigned short* __restrict__ Wlo) {
    int id = blockIdx.x * 256 + threadIdx.x;   // mat*65536 + k4*512 + n
    int mat = id >> 16;
    int k4 = (id >> 9) & 127;
    int n = id & 511;
    const float* W = (mat & 1) ? W2 : W1;
    const float* base = W + (size_t)(mat >> 1) * DIM * DIM;
    u16x4 h, l;
#pragma unroll
    for (int j = 0; j < 4; j++) {
        float v = base[(size_t)(k4 * 4 + j) * DIM + n];
        unsigned short hh = f32_to_bf16(v);
        h[j] = hh;
        l[j] = f32_to_bf16(v - bf16_to_f32(hh));
    }
    size_t o = ((size_t)mat * DIM + n) * DIM + k4 * 4;
    *reinterpret_cast<u16x4*>(Whi + o) = h;
    *reinterpret_cast<u16x4*>(Wlo + o) = l;
}

// ---------------- xprep: Xbf = bf16(x) (halves layer-0 gather footprint) ----------------
__global__ void xprep(const float* __restrict__ X, unsigned short* __restrict__ Xbf,
                      int total8) {
    int i = blockIdx.x * blockDim.x + threadIdx.x;
    int stride = gridDim.x * blockDim.x;
    for (; i < total8; i += stride) {
        f32x4 v0 = *reinterpret_cast<const f32x4*>(X + (size_t)i * 8);
        f32x4 v1 = *reinterpret_cast<const f32x4*>(X + (size_t)i * 8 + 4);
        u16x8 h;
#pragma unroll
        for (int j = 0; j < 4; j++) h[j] = f32_to_bf16(v0[j]);
#pragma unroll
        for (int j = 0; j < 4; j++) h[4 + j] = f32_to_bf16(v1[j]);
        __builtin_nontemporal_store(h, reinterpret_cast<u16x8*>(Xbf + (size_t)i * 8));
    }
}

// ---------------- aggregation over bf16 rows -> A-hi plane ----------------
// MODE 0: T = identity (layer 0, U = bf16(x)).  MODE 1: T(v) = relu(v*a3+c3)
template<int MODE>
__global__ void agg_b(const unsigned short* __restrict__ U,
                      const int* __restrict__ rowptr, const int* __restrict__ colsrc,
                      const float* __restrict__ pa3, const float* __restrict__ pc3,
                      unsigned short* __restrict__ Phi, int N) {
    int n = blockIdx.x;
    int c = threadIdx.x * 4;   // 128 threads * 4 bf16 = 512 cols
    f32x4 a3, c3;
    if (MODE) {
        a3 = *reinterpret_cast<const f32x4*>(pa3 + c);
        c3 = *reinterpret_cast<const f32x4*>(pc3 + c);
    }
    auto ldT = [&](int r) -> f32x4 {
        u16x4 u = *reinterpret_cast<const u16x4*>(U + (size_t)r * DIM + c);
        f32x4 v;
#pragma unroll
        for (int j = 0; j < 4; j++) {
            float f = bf16_to_f32(u[j]);
            v[j] = MODE ? fmaxf(f * a3[j] + c3[j], 0.f) : f;
        }
        return v;
    };
    f32x4 acc = ldT(n);
    int e0 = rowptr[n], e1 = rowptr[n + 1];
    int e = e0;
    for (; e + 4 <= e1; e += 4) {
        int s0 = colsrc[e], s1 = colsrc[e + 1], s2 = colsrc[e + 2], s3 = colsrc[e + 3];
        f32x4 v0 = ldT(s0);
        f32x4 v1 = ldT(s1);
        f32x4 v2 = ldT(s2);
        f32x4 v3 = ldT(s3);
        acc += v0; acc += v1; acc += v2; acc += v3;
    }
    for (; e < e1; e++) acc += ldT(colsrc[e]);
    u16x4 h;
#pragma unroll
    for (int j = 0; j < 4; j++) h[j] = f32_to_bf16(acc[j]);
    __builtin_nontemporal_store(h, reinterpret_cast<u16x4*>(Phi + (size_t)n * DIM + c));
}

// ---------------- convert: Phi = bf16(relu(Y*a + c)) ----------------
__global__ void convert_kernel(const float* __restrict__ Y,
                               const float* __restrict__ pa, const float* __restrict__ pc,
                               unsigned short* __restrict__ Phi, int total8) {
    int i = blockIdx.x * blockDim.x + threadIdx.x;
    int stride = gridDim.x * blockDim.x;
    for (; i < total8; i += stride) {
        int cb = (i & 63) * 8;
        f32x4 v0 = __builtin_nontemporal_load(reinterpret_cast<const f32x4*>(Y + (size_t)i * 8));
        f32x4 v1 = __builtin_nontemporal_load(reinterpret_cast<const f32x4*>(Y + (size_t)i * 8 + 4));
        f32x4 a0 = *reinterpret_cast<const f32x4*>(pa + cb);
        f32x4 a1 = *reinterpret_cast<const f32x4*>(pa + cb + 4);
        f32x4 c0 = *reinterpret_cast<const f32x4*>(pc + cb);
        f32x4 c1 = *reinterpret_cast<const f32x4*>(pc + cb + 4);
        u16x8 h;
#pragma unroll
        for (int j = 0; j < 4; j++)
            h[j] = f32_to_bf16(fmaxf(v0[j] * a0[j] + c0[j], 0.f));
#pragma unroll
        for (int j = 0; j < 4; j++)
            h[4 + j] = f32_to_bf16(fmaxf(v1[j] * a1[j] + c1[j], 0.f));
        __builtin_nontemporal_store(h, reinterpret_cast<u16x8*>(Phi + (size_t)i * 8));
    }
}

// ---------------- GEMM (2-pass): Y = Ahi @ (Whi + Wlo) + bias, + column stats ----------
template<int NTY>
__global__ __launch_bounds__(256, 3)
void gemm_kernel(const unsigned short* __restrict__ Ahi,
                 const unsigned short* __restrict__ Bhi,
                 const unsigned short* __restrict__ Blo,
                 const float* __restrict__ bias,
                 float* __restrict__ Y,
                 float* __restrict__ ssum, float* __restrict__ ssq,
                 int M) {
    __shared__ unsigned short lds[3 * GBM * GBK];   // 48 KB
    unsigned short* sAhi = lds;
    unsigned short* sBhi = lds + GBM * GBK;
    unsigned short* sBlo = lds + 2 * GBM * GBK;

    const int tid = threadIdx.x;
    const int lane = tid & 63;
    const int wave = tid >> 6;
    const int wm = wave >> 1, wn = wave & 1;

    // bijective swizzle: b -> (g = m-panel, j = n-block), g%8 == b%8 (same XCD)
    const int b = blockIdx.x;
    const int xcd = b & 7;
    const int slot = b >> 3;
    const int g = (slot >> 2) * 8 + xcd;
    const int j = slot & 3;
    const int m0 = g * GBM;
    const int n0 = j * GBN;

    const int lrow = lane >> 3;                         // 0..7: row within 8-row group
    const int lkc = ((lane & 7) ^ lrow) * 8;            // pre-swizzled source col chunk

    f32x4 acc[4][4];
#pragma unroll
    for (int i = 0; i < 4; i++)
#pragma unroll
        for (int jj = 0; jj < 4; jj++) acc[i][jj] = (f32x4){0.f, 0.f, 0.f, 0.f};

    for (int kt = 0; kt < DIM; kt += GBK) {
        __syncthreads();
#pragma unroll
        for (int i = 0; i < 4; i++) {
            int r = wave * 8 + i * 32 + lrow;                 // tile row 0..127
            int ldso = wave * 512 + i * 2048;                 // wave-uniform LDS elem offset
            size_t ga = (size_t)(m0 + r) * DIM + kt + lkc;
            size_t gb = (size_t)(n0 + r) * DIM + kt + lkc;
            gl_lds16(Ahi + ga, sAhi + ldso);
            gl_lds16(Bhi + gb, sBhi + ldso);
            gl_lds16(Blo + gb, sBlo + ldso);
        }
        __syncthreads();
#pragma unroll
        for (int ks = 0; ks < 2; ks++) {
            const int kk = ks * 32 + (lane >> 4) * 8;
            const int ar = wm * 64 + (lane & 15);
            const int br = wn * 64 + (lane & 15);
            bf16x8 bh[4], bl[4];
#pragma unroll
            for (int f = 0; f < 4; f++) {
                int rb = br + f * 16;
                int ob = rb * GBK + (kk ^ ((rb & 7) << 3));
                bh[f] = *reinterpret_cast<const bf16x8*>(&sBhi[ob]);
                bl[f] = *reinterpret_cast<const bf16x8*>(&sBlo[ob]);
            }
#pragma unroll
            for (int mf = 0; mf < 4; mf++) {
                int ra = ar + mf * 16;
                int oa = ra * GBK + (kk ^ ((ra & 7) << 3));
                bf16x8 a = *reinterpret_cast<const bf16x8*>(&sAhi[oa]);
#pragma unroll
                for (int nf = 0; nf < 4; nf++) {
                    acc[mf][nf] = __builtin_amdgcn_mfma_f32_16x16x32_bf16(a, bl[nf], acc[mf][nf], 0, 0, 0);
                    acc[mf][nf] = __builtin_amdgcn_mfma_f32_16x16x32_bf16(a, bh[nf], acc[mf][nf], 0, 0, 0);
                }
            }
        }
    }

    // epilogue: bias add, store, column stats
    const int ln16 = lane & 15;
    const int lg = lane >> 4;
#pragma unroll
    for (int nf = 0; nf < 4; nf++) {
        int col = n0 + wn * 64 + nf * 16 + ln16;
        float bv = bias[col];
        float s = 0.f, q = 0.f;
#pragma unroll
        for (int mf = 0; mf < 4; mf++) {
#pragma unroll
            for (int r = 0; r < 4; r++) {
                int row = m0 + wm * 64 + mf * 16 + lg * 4 + r;
                if (row < M) {
                    float v = acc[mf][nf][r] + bv;
                    if (NTY)
                        __builtin_nontemporal_store(v, &Y[(size_t)row * DIM + col]);
                    else
                        Y[(size_t)row * DIM + col] = v;
                    s += v; q += v * v;
                }
            }
        }
        s += __shfl_xor(s, 16);
        s += __shfl_xor(s, 32);
        q += __shfl_xor(q, 16);
        q += __shfl_xor(q, 32);
        if (lg == 0) {
            atomicAdd(&ssum[col], s);
            atomicAdd(&ssq[col], q);
        }
    }
}

// ---------------- column stats of u = relu?(Y*a + c); optionally store u as bf16 ----------
template<int RELU, int STORE>
__global__ void ustats_kernel(const float* __restrict__ Y,
                              const float* __restrict__ pa, const float* __restrict__ pc,
                              float* __restrict__ ssum, float* __restrict__ ssq,
                              unsigned short* __restrict__ U,
                              int M, int chunk) {
    int d = blockIdx.x * blockDim.x + threadIdx.x;
    int r0 = blockIdx.y * chunk;
    int r1 = r0 + chunk; if (r1 > M) r1 = M;
    float a = pa[d], c = pc[d];
    float s = 0.f, q = 0.f;
    for (int r = r0; r < r1; r++) {
        float v = Y[(size_t)r * DIM + d] * a + c;
        if (RELU) v = fmaxf(v, 0.f);
        s += v; q += v * v;
        if (STORE) U[(size_t)r * DIM + d] = f32_to_bf16(v);
    }
    atomicAdd(&ssum[d], s);
    atomicAdd(&ssq[d], q);
}

// ---------------- BN params: a = g*rsqrt(var+eps), c = beta - mean*a ----------------
__global__ void params_kernel(const float* __restrict__ ssum, const float* __restrict__ ssq,
                              const float* __restrict__ g, const float* __restrict__ b,
                              float* __restrict__ pa, float* __restrict__ pc, float invN) {
    int d = threadIdx.x + blockIdx.x * blockDim.x;
    float m = ssum[d] * invN;
    float var = ssq[d] * invN - m * m;
    var = fmaxf(var, 0.f);
    float s = rsqrtf(var + 1e-5f);
    float a = g[d] * s;
    pa[d] = a;
    pc[d] = b[d] - m * a;
}

// ---------------- final in-place: out = (out*a2+c2)*a3+c3 ----------------
__global__ void finalize_kernel(float* __restrict__ Y,
                                const float* __restrict__ pa2, const float* __restrict__ pc2,
                                const float* __restrict__ pa3, const float* __restrict__ pc3,
                                int total4) {
    int i = blockIdx.x * blockDim.x + threadIdx.x;
    int stride = gridDim.x * blockDim.x;
    for (; i < total4; i += stride) {
        int c = (i & 127) * 4;
        f32x4 v = *reinterpret_cast<f32x4*>(Y + (size_t)i * 4);
#pragma unroll
        for (int j = 0; j < 4; j++) {
            float f = v[j] * pa2[c + j] + pc2[c + j];
            v[j] = f * pa3[c + j] + pc3[c + j];
        }
        *reinterpret_cast<f32x4*>(Y + (size_t)i * 4) = v;
    }
}

extern "C" void kernel_launch(void* const* d_in, const int* in_sizes, int n_in,
                              void* d_out, int out_size, void* d_ws, size_t ws_size,
                              hipStream_t stream) {
    const float* x   = (const float*)d_in[0];
    const int*   ei  = (const int*)d_in[1];
    const float* W1  = (const float*)d_in[2];
    const float* b1  = (const float*)d_in[3];
    const float* g1  = (const float*)d_in[4];
    const float* be1 = (const float*)d_in[5];
    const float* W2  = (const float*)d_in[6];
    const float* b2  = (const float*)d_in[7];
    const float* g2  = (const float*)d_in[8];
    const float* be2 = (const float*)d_in[9];
    const float* ng  = (const float*)d_in[10];
    const float* nb  = (const float*)d_in[11];

    const int N = in_sizes[0] / DIM;
    const int E = in_sizes[1] / 2;

    char* ws = (char*)d_ws;
    size_t off = 0;
    auto alloc = [&](size_t bytes) -> void* {
        void* p = ws + off;
        off += (bytes + 255) & ~(size_t)255;
        return p;
    };
    unsigned short* Phi = (unsigned short*)alloc((size_t)N * DIM * 2);
    unsigned short* Xbf = (unsigned short*)alloc((size_t)N * DIM * 2);
    float* y1 = (float*)alloc((size_t)N * DIM * 4);
    unsigned short* Whi = (unsigned short*)alloc(6ull * DIM * DIM * 2);
    unsigned short* Wlo = (unsigned short*)alloc(6ull * DIM * DIM * 2);
    int* rowptr = (int*)alloc((size_t)(N + 1) * 4);
    int* counts = (int*)alloc((size_t)N * 4);
    int* cursor = (int*)alloc((size_t)N * 4);
    int* colsrc = (int*)alloc((size_t)E * 4);
    int* bsum   = (int*)alloc(1024 * 4);
    float* stats = (float*)alloc(9ull * 1024 * 4);
    float* prm = (float*)alloc(6ull * DIM * 4);

    // U (bf16 u-activations, 51 MB) aliases y1: y1 dead after convert(l); U written by
    // ustats(l), read by agg_b(l+1) before gemm1 rewrites y1. Lifetimes disjoint.
    unsigned short* U = (unsigned short*)y1;

    float* Yout = (float*)d_out;
    float* pa1 = prm,         *pc1 = prm + DIM;
    float* pa2 = prm + 2*DIM, *pc2 = prm + 3*DIM;
    float* pa3 = prm + 4*DIM, *pc3 = prm + 5*DIM;

    hipMemsetAsync(counts, 0, (size_t)N * 4, stream);
    hipMemsetAsync(stats, 0, 9ull * 1024 * 4, stream);

    const int NB = (N + 255) / 256;   // 196 scan blocks (<= 256)

    wprep<<<1536, 256, 0, stream>>>(W1, W2, Whi, Wlo);
    xprep<<<2048, 256, 0, stream>>>(x, Xbf, N * DIM / 8);
    csr_count<<<(E + 255) / 256, 256, 0, stream>>>(ei, counts, E);
    scan1<<<NB, 256, 0, stream>>>(counts, rowptr, bsum, N);
    scan2<<<1, 256, 0, stream>>>(bsum, NB);
    scan3<<<NB, 256, 0, stream>>>(bsum, rowptr, cursor, N, E);
    csr_fill<<<(E + 255) / 256, 256, 0, stream>>>(ei, cursor, colsrc, E);

    const float invN = 1.0f / (float)N;
    const int Gm = ((N + GBM - 1) / GBM + 7) & ~7;
    const int gemm_blocks = Gm * 4;
    const int uchunk = (N + 199) / 200;
    const int total8 = N * DIM / 8;

    for (int l = 0; l < NLAYERS; l++) {
        float* st1 = stats + (size_t)l * 3 * 1024;
        float* st2 = st1 + 1024;
        float* st3 = st2 + 1024;
        if (l == 0)
            agg_b<0><<<N, 128, 0, stream>>>(Xbf, rowptr, colsrc, nullptr, nullptr, Phi, N);
        else
            agg_b<1><<<N, 128, 0, stream>>>(U, rowptr, colsrc, pa3, pc3, Phi, N);
        gemm_kernel<1><<<gemm_blocks, 256, 0, stream>>>(Phi,
            Whi + (size_t)(l * 2) * DIM * DIM, Wlo + (size_t)(l * 2) * DIM * DIM,
            b1 + l * DIM, y1, st1, st1 + 512, N);
        params_kernel<<<1, 512, 0, stream>>>(st1, st1 + 512, g1 + l * DIM, be1 + l * DIM,
                                             pa1, pc1, invN);
        convert_kernel<<<2048, 256, 0, stream>>>(y1, pa1, pc1, Phi, total8);
        gemm_kernel<0><<<gemm_blocks, 256, 0, stream>>>(Phi,
            Whi + (size_t)(l * 2 + 1) * DIM * DIM, Wlo + (size_t)(l * 2 + 1) * DIM * DIM,
            b2 + l * DIM, Yout, st2, st2 + 512, N);
        params_kernel<<<1, 512, 0, stream>>>(st2, st2 + 512, g2 + l * DIM, be2 + l * DIM,
                                             pa2, pc2, invN);
        if (l < NLAYERS - 1)
            ustats_kernel<1, 1><<<dim3(2, 200), 256, 0, stream>>>(Yout, pa2, pc2,
                                                                  st3, st3 + 512, U, N, uchunk);
        else
            ustats_kernel<0, 0><<<dim3(2, 200), 256, 0, stream>>>(Yout, pa2, pc2,
                                                                  st3, st3 + 512, U, N, uchunk);
        params_kernel<<<1, 512, 0, stream>>>(st3, st3 + 512, ng + l * DIM, nb + l * DIM,
                                             pa3, pc3, invN);
    }
    finalize_kernel<<<2048, 256, 0, stream>>>(Yout, pa2, pc2, pa3, pc3, N * DIM / 4);
}

// Round 12
// 1468.791 us; speedup vs baseline: 1.5166x; 1.0131x over previous
//
#include <hip/hip_runtime.h>
#include <cstdint>
#include <cstddef>

#define DIM 512
#define NLAYERS 3
#define BM 256
#define BN 128
#define BK 32
// per-buffer LDS elems: A 256*32 + Bhi 128*32 + Blo 128*32
#define LDS_A 0
#define LDS_BH 8192
#define LDS_BL 12288
#define LDS_BUF 16384

typedef float f32x4 __attribute__((ext_vector_type(4)));
typedef short bf16x8 __attribute__((ext_vector_type(8)));
typedef unsigned short u16x4 __attribute__((ext_vector_type(4)));
typedef unsigned short u16x8 __attribute__((ext_vector_type(8)));

__device__ __forceinline__ unsigned short f32_to_bf16(float f) {
    unsigned u = __float_as_uint(f);
    u += 0x7fffu + ((u >> 16) & 1u);
    return (unsigned short)(u >> 16);
}
__device__ __forceinline__ float bf16_to_f32(unsigned short h) {
    return __uint_as_float(((unsigned)h) << 16);
}

// async global->LDS, 16B per lane; LDS dest = wave-uniform base + lane*16 (linear).
__device__ __forceinline__ void gl_lds16(const unsigned short* g, unsigned short* l) {
    __builtin_amdgcn_global_load_lds(
        (const __attribute__((address_space(1))) void*)g,
        (__attribute__((address_space(3))) void*)l,
        16, 0, 0);
}

// ---------------- CSR build ----------------
__global__ void csr_count(const int* __restrict__ ei, int* __restrict__ counts, int E) {
    int e = blockIdx.x * 256 + threadIdx.x;
    if (e < E) atomicAdd(&counts[ei[E + e]], 1);
}

__global__ void scan1(const int* __restrict__ counts, int* __restrict__ rowptr,
                      int* __restrict__ bsum, int N) {
    __shared__ int sh[256];
    int t = threadIdx.x;
    int i = blockIdx.x * 256 + t;
    int v = (i < N) ? counts[i] : 0;
    sh[t] = v;
    __syncthreads();
    for (int d = 1; d < 256; d <<= 1) {
        int u = (t >= d) ? sh[t - d] : 0;
        __syncthreads();
        sh[t] += u;
        __syncthreads();
    }
    if (i < N) rowptr[i] = sh[t] - v;
    if (t == 255) bsum[blockIdx.x] = sh[255];
}

__global__ void scan2(int* __restrict__ bsum, int NB) {
    __shared__ int sh[256];
    int t = threadIdx.x;
    int v = (t < NB) ? bsum[t] : 0;
    sh[t] = v;
    __syncthreads();
    for (int d = 1; d < 256; d <<= 1) {
        int u = (t >= d) ? sh[t - d] : 0;
        __syncthreads();
        sh[t] += u;
        __syncthreads();
    }
    if (t < NB) bsum[t] = sh[t] - v;
}

__global__ void scan3(const int* __restrict__ bsum, int* __restrict__ rowptr,
                      int* __restrict__ cursor, int N, int E) {
    int i = blockIdx.x * 256 + threadIdx.x;
    if (i < N) {
        int v = rowptr[i] + bsum[blockIdx.x];
        rowptr[i] = v;
        cursor[i] = v;
    }
    if (blockIdx.x == 0 && threadIdx.x == 0) rowptr[N] = E;
}

__global__ void csr_fill(const int* __restrict__ ei, int* __restrict__ cursor,
                         int* __restrict__ colsrc, int E) {
    int e = blockIdx.x * 256 + threadIdx.x;
    if (e < E) {
        int s = ei[e], d = ei[E + e];
        int p = atomicAdd(&cursor[d], 1);
        colsrc[p] = s;
    }
}

// ---------------- weight prep: W[l][k][n] fp32 -> Wt_hi/lo[mat][n][k] bf16 ----------------
__global__ void wprep(const float* __restrict__ W1, const float* __restrict__ W2,
                      unsigned short* __restrict__ Whi, unsigned short* __restrict__ Wlo) {
    int id = blockIdx.x * 256 + threadIdx.x;
    int mat = id >> 16;
    int k4 = (id >> 9) & 127;
    int n = id & 511;
    const float* W = (mat & 1) ? W2 : W1;
    const float* base = W + (size_t)(mat >> 1) * DIM * DIM;
    u16x4 h, l;
#pragma unroll
    for (int j = 0; j < 4; j++) {
        float v = base[(size_t)(k4 * 4 + j) * DIM + n];
        unsigned short hh = f32_to_bf16(v);
        h[j] = hh;
        l[j] = f32_to_bf16(v - bf16_to_f32(hh));
    }
    size_t o = ((size_t)mat * DIM + n) * DIM + k4 * 4;
    *reinterpret_cast<u16x4*>(Whi + o) = h;
    *reinterpret_cast<u16x4*>(Wlo + o) = l;
}

// ---------------- xprep: Xbf = bf16(x) ----------------
__global__ void xprep(const float* __restrict__ X, unsigned short* __restrict__ Xbf,
                      int total8) {
    int i = blockIdx.x * blockDim.x + threadIdx.x;
    int stride = gridDim.x * blockDim.x;
    for (; i < total8; i += stride) {
        f32x4 v0 = *reinterpret_cast<const f32x4*>(X + (size_t)i * 8);
        f32x4 v1 = *reinterpret_cast<const f32x4*>(X + (size_t)i * 8 + 4);
        u16x8 h;
#pragma unroll
        for (int j = 0; j < 4; j++) h[j] = f32_to_bf16(v0[j]);
#pragma unroll
        for (int j = 0; j < 4; j++) h[4 + j] = f32_to_bf16(v1[j]);
        __builtin_nontemporal_store(h, reinterpret_cast<u16x8*>(Xbf + (size_t)i * 8));
    }
}

// ---------------- aggregation over bf16 rows -> A-hi plane ----------------
template<int MODE>
__global__ void agg_b(const unsigned short* __restrict__ U,
                      const int* __restrict__ rowptr, const int* __restrict__ colsrc,
                      const float* __restrict__ pa3, const float* __restrict__ pc3,
                      unsigned short* __restrict__ Phi, int N) {
    int n = blockIdx.x;
    int c = threadIdx.x * 4;
    f32x4 a3, c3;
    if (MODE) {
        a3 = *reinterpret_cast<const f32x4*>(pa3 + c);
        c3 = *reinterpret_cast<const f32x4*>(pc3 + c);
    }
    auto ldT = [&](int r) -> f32x4 {
        u16x4 u = *reinterpret_cast<const u16x4*>(U + (size_t)r * DIM + c);
        f32x4 v;
#pragma unroll
        for (int j = 0; j < 4; j++) {
            float f = bf16_to_f32(u[j]);
            v[j] = MODE ? fmaxf(f * a3[j] + c3[j], 0.f) : f;
        }
        return v;
    };
    f32x4 acc = ldT(n);
    int e0 = rowptr[n], e1 = rowptr[n + 1];
    int e = e0;
    for (; e + 4 <= e1; e += 4) {
        int s0 = colsrc[e], s1 = colsrc[e + 1], s2 = colsrc[e + 2], s3 = colsrc[e + 3];
        f32x4 v0 = ldT(s0);
        f32x4 v1 = ldT(s1);
        f32x4 v2 = ldT(s2);
        f32x4 v3 = ldT(s3);
        acc += v0; acc += v1; acc += v2; acc += v3;
    }
    for (; e < e1; e++) acc += ldT(colsrc[e]);
    u16x4 h;
#pragma unroll
    for (int j = 0; j < 4; j++) h[j] = f32_to_bf16(acc[j]);
    __builtin_nontemporal_store(h, reinterpret_cast<u16x4*>(Phi + (size_t)n * DIM + c));
}

// ---------------- convert: Phi = bf16(relu(Y*a + c)) ----------------
__global__ void convert_kernel(const float* __restrict__ Y,
                               const float* __restrict__ pa, const float* __restrict__ pc,
                               unsigned short* __restrict__ Phi, int total8) {
    int i = blockIdx.x * blockDim.x + threadIdx.x;
    int stride = gridDim.x * blockDim.x;
    for (; i < total8; i += stride) {
        int cb = (i & 63) * 8;
        f32x4 v0 = __builtin_nontemporal_load(reinterpret_cast<const f32x4*>(Y + (size_t)i * 8));
        f32x4 v1 = __builtin_nontemporal_load(reinterpret_cast<const f32x4*>(Y + (size_t)i * 8 + 4));
        f32x4 a0 = *reinterpret_cast<const f32x4*>(pa + cb);
        f32x4 a1 = *reinterpret_cast<const f32x4*>(pa + cb + 4);
        f32x4 c0 = *reinterpret_cast<const f32x4*>(pc + cb);
        f32x4 c1 = *reinterpret_cast<const f32x4*>(pc + cb + 4);
        u16x8 h;
#pragma unroll
        for (int j = 0; j < 4; j++)
            h[j] = f32_to_bf16(fmaxf(v0[j] * a0[j] + c0[j], 0.f));
#pragma unroll
        for (int j = 0; j < 4; j++)
            h[4 + j] = f32_to_bf16(fmaxf(v1[j] * a1[j] + c1[j], 0.f));
        __builtin_nontemporal_store(h, reinterpret_cast<u16x8*>(Phi + (size_t)i * 8));
    }
}

// ---------------- GEMM: 256x128 tile, BK=32, double-buffered, stage-early ----------
// Y = Ahi @ (Whi + Wlo) + bias, + column stats. 64 KB LDS -> 2 blocks/CU.
// Swizzle (rule #21, both sides): stage source col chunk ^= (row>>1)&3 (LDS dest
// linear); ds_read slot = (lane>>4) ^ ((lane&15)>>1)&3 -> 2-way residual (free).
template<int NTY>
__global__ __launch_bounds__(256, 2)
void gemm_kernel(const unsigned short* __restrict__ Ahi,
                 const unsigned short* __restrict__ Bhi,
                 const unsigned short* __restrict__ Blo,
                 const float* __restrict__ bias,
                 float* __restrict__ Y,
                 float* __restrict__ ssum, float* __restrict__ ssq,
                 int M) {
    __shared__ unsigned short lds[2 * LDS_BUF];   // 64 KB

    const int tid = threadIdx.x;
    const int lane = tid & 63;
    const int wave = tid >> 6;
    const int wm = wave >> 1, wn = wave & 1;

    // bijective swizzle: b -> (g = m-panel, j = n-block), g%8 == b%8 (same XCD)
    const int b = blockIdx.x;
    const int xcd = b & 7;
    const int slot_ = b >> 3;
    const int g = (slot_ >> 2) * 8 + xcd;
    const int j = slot_ & 3;
    const int m0 = g * BM;
    const int n0 = j * BN;

    // stage lane mapping: 4 lanes per 64B row; source chunk pre-swizzled
    const int srow = lane >> 2;          // 0..15
    const int sc = lane & 3;             // 16B chunk 0..3

    // ds_read mapping
    const int r15 = lane & 15;
    const int q = lane >> 4;
    const int rslot = ((q ^ ((r15 >> 1) & 3))) * 8;   // elem offset within 32-elem row

    f32x4 acc[8][4];
#pragma unroll
    for (int i = 0; i < 8; i++)
#pragma unroll
        for (int jj = 0; jj < 4; jj++) acc[i][jj] = (f32x4){0.f, 0.f, 0.f, 0.f};

    auto STAGE = [&](int bufb, int kt) {
        unsigned short* L = lds + bufb * LDS_BUF;
#pragma unroll
        for (int i = 0; i < 4; i++) {              // A: 256 rows
            int r = wave * 64 + i * 16 + srow;
            int colc = sc ^ ((r >> 1) & 3);
            gl_lds16(Ahi + (size_t)(m0 + r) * DIM + kt + colc * 8,
                     L + LDS_A + wave * 2048 + i * 512);
        }
#pragma unroll
        for (int i = 0; i < 2; i++) {              // Bhi/Blo: 128 rows each
            int r = wave * 32 + i * 16 + srow;
            int colc = sc ^ ((r >> 1) & 3);
            size_t go = (size_t)(n0 + r) * DIM + kt + colc * 8;
            gl_lds16(Bhi + go, L + LDS_BH + wave * 1024 + i * 512);
            gl_lds16(Blo + go, L + LDS_BL + wave * 1024 + i * 512);
        }
    };

    STAGE(0, 0);
    __syncthreads();

    int buf = 0;
    for (int t = 0; t < DIM / BK; t++) {
        if (t < DIM / BK - 1) STAGE(buf ^ 1, (t + 1) * BK);
        unsigned short* L = lds + buf * LDS_BUF;
        bf16x8 bh[4], bl[4];
#pragma unroll
        for (int nf = 0; nf < 4; nf++) {
            int rb = wn * 64 + nf * 16 + r15;
            bh[nf] = *reinterpret_cast<const bf16x8*>(&L[LDS_BH + rb * 32 + rslot]);
            bl[nf] = *reinterpret_cast<const bf16x8*>(&L[LDS_BL + rb * 32 + rslot]);
        }
#pragma unroll
        for (int mf = 0; mf < 8; mf++) {
            int ra = wm * 128 + mf * 16 + r15;
            bf16x8 a = *reinterpret_cast<const bf16x8*>(&L[LDS_A + ra * 32 + rslot]);
#pragma unroll
            for (int nf = 0; nf < 4; nf++) {
                acc[mf][nf] = __builtin_amdgcn_mfma_f32_16x16x32_bf16(a, bl[nf], acc[mf][nf], 0, 0, 0);
                acc[mf][nf] = __builtin_amdgcn_mfma_f32_16x16x32_bf16(a, bh[nf], acc[mf][nf], 0, 0, 0);
            }
        }
        __syncthreads();
        buf ^= 1;
    }

    // epilogue: bias add, store, column stats
    const int ln16 = lane & 15;
    const int lg = lane >> 4;
#pragma unroll
    for (int nf = 0; nf < 4; nf++) {
        int col = n0 + wn * 64 + nf * 16 + ln16;
        float bv = bias[col];
        float s = 0.f, qq = 0.f;
#pragma unroll
        for (int mf = 0; mf < 8; mf++) {
#pragma unroll
            for (int r = 0; r < 4; r++) {
                int row = m0 + wm * 128 + mf * 16 + lg * 4 + r;
                if (row < M) {
                    float v = acc[mf][nf][r] + bv;
                    if (NTY)
                        __builtin_nontemporal_store(v, &Y[(size_t)row * DIM + col]);
                    else
                        Y[(size_t)row * DIM + col] = v;
                    s += v; qq += v * v;
                }
            }
        }
        s += __shfl_xor(s, 16);
        s += __shfl_xor(s, 32);
        qq += __shfl_xor(qq, 16);
        qq += __shfl_xor(qq, 32);
        if (lg == 0) {
            atomicAdd(&ssum[col], s);
            atomicAdd(&ssq[col], qq);
        }
    }
}

// ---------------- column stats of u = relu?(Y*a + c); optionally store u as bf16 ----------
template<int RELU, int STORE>
__global__ void ustats_kernel(const float* __restrict__ Y,
                              const float* __restrict__ pa, const float* __restrict__ pc,
                              float* __restrict__ ssum, float* __restrict__ ssq,
                              unsigned short* __restrict__ U,
                              int M, int chunk) {
    int d = blockIdx.x * blockDim.x + threadIdx.x;
    int r0 = blockIdx.y * chunk;
    int r1 = r0 + chunk; if (r1 > M) r1 = M;
    float a = pa[d], c = pc[d];
    float s = 0.f, q = 0.f;
    for (int r = r0; r < r1; r++) {
        float v = Y[(size_t)r * DIM + d] * a + c;
        if (RELU) v = fmaxf(v, 0.f);
        s += v; q += v * v;
        if (STORE) U[(size_t)r * DIM + d] = f32_to_bf16(v);
    }
    atomicAdd(&ssum[d], s);
    atomicAdd(&ssq[d], q);
}

// ---------------- BN params ----------------
__global__ void params_kernel(const float* __restrict__ ssum, const float* __restrict__ ssq,
                              const float* __restrict__ g, const float* __restrict__ b,
                              float* __restrict__ pa, float* __restrict__ pc, float invN) {
    int d = threadIdx.x + blockIdx.x * blockDim.x;
    float m = ssum[d] * invN;
    float var = ssq[d] * invN - m * m;
    var = fmaxf(var, 0.f);
    float s = rsqrtf(var + 1e-5f);
    float a = g[d] * s;
    pa[d] = a;
    pc[d] = b[d] - m * a;
}

// ---------------- final in-place: out = (out*a2+c2)*a3+c3 ----------------
__global__ void finalize_kernel(float* __restrict__ Y,
                                const float* __restrict__ pa2, const float* __restrict__ pc2,
                                const float* __restrict__ pa3, const float* __restrict__ pc3,
                                int total4) {
    int i = blockIdx.x * blockDim.x + threadIdx.x;
    int stride = gridDim.x * blockDim.x;
    for (; i < total4; i += stride) {
        int c = (i & 127) * 4;
        f32x4 v = *reinterpret_cast<f32x4*>(Y + (size_t)i * 4);
#pragma unroll
        for (int j = 0; j < 4; j++) {
            float f = v[j] * pa2[c + j] + pc2[c + j];
            v[j] = f * pa3[c + j] + pc3[c + j];
        }
        *reinterpret_cast<f32x4*>(Y + (size_t)i * 4) = v;
    }
}

extern "C" void kernel_launch(void* const* d_in, const int* in_sizes, int n_in,
                              void* d_out, int out_size, void* d_ws, size_t ws_size,
                              hipStream_t stream) {
    const float* x   = (const float*)d_in[0];
    const int*   ei  = (const int*)d_in[1];
    const float* W1  = (const float*)d_in[2];
    const float* b1  = (const float*)d_in[3];
    const float* g1  = (const float*)d_in[4];
    const float* be1 = (const float*)d_in[5];
    const float* W2  = (const float*)d_in[6];
    const float* b2  = (const float*)d_in[7];
    const float* g2  = (const float*)d_in[8];
    const float* be2 = (const float*)d_in[9];
    const float* ng  = (const float*)d_in[10];
    const float* nb  = (const float*)d_in[11];

    const int N = in_sizes[0] / DIM;
    const int E = in_sizes[1] / 2;

    char* ws = (char*)d_ws;
    size_t off = 0;
    auto alloc = [&](size_t bytes) -> void* {
        void* p = ws + off;
        off += (bytes + 255) & ~(size_t)255;
        return p;
    };
    unsigned short* Phi = (unsigned short*)alloc((size_t)N * DIM * 2);
    unsigned short* Xbf = (unsigned short*)alloc((size_t)N * DIM * 2);  // also absorbs padded A reads
    float* y1 = (float*)alloc((size_t)N * DIM * 4);
    unsigned short* Whi = (unsigned short*)alloc(6ull * DIM * DIM * 2);
    unsigned short* Wlo = (unsigned short*)alloc(6ull * DIM * DIM * 2);
    int* rowptr = (int*)alloc((size_t)(N + 1) * 4);
    int* counts = (int*)alloc((size_t)N * 4);
    int* cursor = (int*)alloc((size_t)N * 4);
    int* colsrc = (int*)alloc((size_t)E * 4);
    int* bsum   = (int*)alloc(1024 * 4);
    float* stats = (float*)alloc(9ull * 1024 * 4);
    float* prm = (float*)alloc(6ull * DIM * 4);

    unsigned short* U = (unsigned short*)y1;   // disjoint lifetime alias (see R8)

    float* Yout = (float*)d_out;
    float* pa1 = prm,         *pc1 = prm + DIM;
    float* pa2 = prm + 2*DIM, *pc2 = prm + 3*DIM;
    float* pa3 = prm + 4*DIM, *pc3 = prm + 5*DIM;

    hipMemsetAsync(counts, 0, (size_t)N * 4, stream);
    hipMemsetAsync(stats, 0, 9ull * 1024 * 4, stream);

    const int NBs = (N + 255) / 256;

    wprep<<<1536, 256, 0, stream>>>(W1, W2, Whi, Wlo);
    xprep<<<2048, 256, 0, stream>>>(x, Xbf, N * DIM / 8);
    csr_count<<<(E + 255) / 256, 256, 0, stream>>>(ei, counts, E);
    scan1<<<NBs, 256, 0, stream>>>(counts, rowptr, bsum, N);
    scan2<<<1, 256, 0, stream>>>(bsum, NBs);
    scan3<<<NBs, 256, 0, stream>>>(bsum, rowptr, cursor, N, E);
    csr_fill<<<(E + 255) / 256, 256, 0, stream>>>(ei, cursor, colsrc, E);

    const float invN = 1.0f / (float)N;
    const int Gm = (((N + BM - 1) / BM) + 7) & ~7;   // 196 -> 200 m-panels
    const int gemm_blocks = Gm * 4;                  // 4 n-blocks of 128
    const int uchunk = (N + 199) / 200;
    const int total8 = N * DIM / 8;

    for (int l = 0; l < NLAYERS; l++) {
        float* st1 = stats + (size_t)l * 3 * 1024;
        float* st2 = st1 + 1024;
        float* st3 = st2 + 1024;
        if (l == 0)
            agg_b<0><<<N, 128, 0, stream>>>(Xbf, rowptr, colsrc, nullptr, nullptr, Phi, N);
        else
            agg_b<1><<<N, 128, 0, stream>>>(U, rowptr, colsrc, pa3, pc3, Phi, N);
        gemm_kernel<1><<<gemm_blocks, 256, 0, stream>>>(Phi,
            Whi + (size_t)(l * 2) * DIM * DIM, Wlo + (size_t)(l * 2) * DIM * DIM,
            b1 + l * DIM, y1, st1, st1 + 512, N);
        params_kernel<<<1, 512, 0, stream>>>(st1, st1 + 512, g1 + l * DIM, be1 + l * DIM,
                                             pa1, pc1, invN);
        convert_kernel<<<2048, 256, 0, stream>>>(y1, pa1, pc1, Phi, total8);
        gemm_kernel<0><<<gemm_blocks, 256, 0, stream>>>(Phi,
            Whi + (size_t)(l * 2 + 1) * DIM * DIM, Wlo + (size_t)(l * 2 + 1) * DIM * DIM,
            b2 + l * DIM, Yout, st2, st2 + 512, N);
        params_kernel<<<1, 512, 0, stream>>>(st2, st2 + 512, g2 + l * DIM, be2 + l * DIM,
                                             pa2, pc2, invN);
        if (l < NLAYERS - 1)
            ustats_kernel<1, 1><<<dim3(2, 200), 256, 0, stream>>>(Yout, pa2, pc2,
                                                                  st3, st3 + 512, U, N, uchunk);
        else
            ustats_kernel<0, 0><<<dim3(2, 200), 256, 0, stream>>>(Yout, pa2, pc2,
                                                                  st3, st3 + 512, U, N, uchunk);
        params_kernel<<<1, 512, 0, stream>>>(st3, st3 + 512, ng + l * DIM, nb + l * DIM,
                                             pa3, pc3, invN);
    }
    finalize_kernel<<<2048, 256, 0, stream>>>(Yout, pa2, pc2, pa3, pc3, N * DIM / 4);
}

// Round 13
// 1366.257 us; speedup vs baseline: 1.6304x; 1.0750x over previous
//
#include <hip/hip_runtime.h>
#include <cstdint>
#include <cstddef>

#define DIM 512
#define NLAYERS 3
#define BM 256
#define BN 128
#define BK 32
#define LDS_A 0
#define LDS_BH 8192
#define LDS_BL 12288
#define LDS_BUF 16384

typedef float f32x4 __attribute__((ext_vector_type(4)));
typedef short bf16x8 __attribute__((ext_vector_type(8)));
typedef unsigned short u16x4 __attribute__((ext_vector_type(4)));
typedef unsigned short u16x8 __attribute__((ext_vector_type(8)));

__device__ __forceinline__ unsigned short f32_to_bf16(float f) {
    unsigned u = __float_as_uint(f);
    u += 0x7fffu + ((u >> 16) & 1u);
    return (unsigned short)(u >> 16);
}
__device__ __forceinline__ float bf16_to_f32(unsigned short h) {
    return __uint_as_float(((unsigned)h) << 16);
}

__device__ __forceinline__ void gl_lds16(const unsigned short* g, unsigned short* l) {
    __builtin_amdgcn_global_load_lds(
        (const __attribute__((address_space(1))) void*)g,
        (__attribute__((address_space(3))) void*)l,
        16, 0, 0);
}

// ---------------- CSR build ----------------
__global__ void csr_count(const int* __restrict__ ei, int* __restrict__ counts, int E) {
    int e = blockIdx.x * 256 + threadIdx.x;
    if (e < E) atomicAdd(&counts[ei[E + e]], 1);
}

__global__ void scan1(const int* __restrict__ counts, int* __restrict__ rowptr,
                      int* __restrict__ bsum, int N) {
    __shared__ int sh[256];
    int t = threadIdx.x;
    int i = blockIdx.x * 256 + t;
    int v = (i < N) ? counts[i] : 0;
    sh[t] = v;
    __syncthreads();
    for (int d = 1; d < 256; d <<= 1) {
        int u = (t >= d) ? sh[t - d] : 0;
        __syncthreads();
        sh[t] += u;
        __syncthreads();
    }
    if (i < N) rowptr[i] = sh[t] - v;
    if (t == 255) bsum[blockIdx.x] = sh[255];
}

__global__ void scan2(int* __restrict__ bsum, int NB) {
    __shared__ int sh[256];
    int t = threadIdx.x;
    int v = (t < NB) ? bsum[t] : 0;
    sh[t] = v;
    __syncthreads();
    for (int d = 1; d < 256; d <<= 1) {
        int u = (t >= d) ? sh[t - d] : 0;
        __syncthreads();
        sh[t] += u;
        __syncthreads();
    }
    if (t < NB) bsum[t] = sh[t] - v;
}

__global__ void scan3(const int* __restrict__ bsum, int* __restrict__ rowptr,
                      int* __restrict__ cursor, int N, int E) {
    int i = blockIdx.x * 256 + threadIdx.x;
    if (i < N) {
        int v = rowptr[i] + bsum[blockIdx.x];
        rowptr[i] = v;
        cursor[i] = v;
    }
    if (blockIdx.x == 0 && threadIdx.x == 0) rowptr[N] = E;
}

__global__ void csr_fill(const int* __restrict__ ei, int* __restrict__ cursor,
                         int* __restrict__ colsrc, int E) {
    int e = blockIdx.x * 256 + threadIdx.x;
    if (e < E) {
        int s = ei[e], d = ei[E + e];
        int p = atomicAdd(&cursor[d], 1);
        colsrc[p] = s;
    }
}

// ---------------- weight prep ----------------
__global__ void wprep(const float* __restrict__ W1, const float* __restrict__ W2,
                      unsigned short* __restrict__ Whi, unsigned short* __restrict__ Wlo) {
    int id = blockIdx.x * 256 + threadIdx.x;
    int mat = id >> 16;
    int k4 = (id >> 9) & 127;
    int n = id & 511;
    const float* W = (mat & 1) ? W2 : W1;
    const float* base = W + (size_t)(mat >> 1) * DIM * DIM;
    u16x4 h, l;
#pragma unroll
    for (int j = 0; j < 4; j++) {
        float v = base[(size_t)(k4 * 4 + j) * DIM + n];
        unsigned short hh = f32_to_bf16(v);
        h[j] = hh;
        l[j] = f32_to_bf16(v - bf16_to_f32(hh));
    }
    size_t o = ((size_t)mat * DIM + n) * DIM + k4 * 4;
    *reinterpret_cast<u16x4*>(Whi + o) = h;
    *reinterpret_cast<u16x4*>(Wlo + o) = l;
}

// ---------------- xprep: Xbf = bf16(x) ----------------
__global__ void xprep(const float* __restrict__ X, unsigned short* __restrict__ Xbf,
                      int total8) {
    int i = blockIdx.x * blockDim.x + threadIdx.x;
    int stride = gridDim.x * blockDim.x;
    for (; i < total8; i += stride) {
        f32x4 v0 = *reinterpret_cast<const f32x4*>(X + (size_t)i * 8);
        f32x4 v1 = *reinterpret_cast<const f32x4*>(X + (size_t)i * 8 + 4);
        u16x8 h;
#pragma unroll
        for (int j = 0; j < 4; j++) h[j] = f32_to_bf16(v0[j]);
#pragma unroll
        for (int j = 0; j < 4; j++) h[4 + j] = f32_to_bf16(v1[j]);
        __builtin_nontemporal_store(h, reinterpret_cast<u16x8*>(Xbf + (size_t)i * 8));
    }
}

// ---------------- aggregation over bf16 rows -> A-hi plane ----------------
template<int MODE>
__global__ void agg_b(const unsigned short* __restrict__ U,
                      const int* __restrict__ rowptr, const int* __restrict__ colsrc,
                      const float* __restrict__ pa3, const float* __restrict__ pc3,
                      unsigned short* __restrict__ Phi, int N) {
    int n = blockIdx.x;
    int c = threadIdx.x * 4;
    f32x4 a3, c3;
    if (MODE) {
        a3 = *reinterpret_cast<const f32x4*>(pa3 + c);
        c3 = *reinterpret_cast<const f32x4*>(pc3 + c);
    }
    auto ldT = [&](int r) -> f32x4 {
        u16x4 u = *reinterpret_cast<const u16x4*>(U + (size_t)r * DIM + c);
        f32x4 v;
#pragma unroll
        for (int j = 0; j < 4; j++) {
            float f = bf16_to_f32(u[j]);
            v[j] = MODE ? fmaxf(f * a3[j] + c3[j], 0.f) : f;
        }
        return v;
    };
    f32x4 acc = ldT(n);
    int e0 = rowptr[n], e1 = rowptr[n + 1];
    int e = e0;
    for (; e + 4 <= e1; e += 4) {
        int s0 = colsrc[e], s1 = colsrc[e + 1], s2 = colsrc[e + 2], s3 = colsrc[e + 3];
        f32x4 v0 = ldT(s0);
        f32x4 v1 = ldT(s1);
        f32x4 v2 = ldT(s2);
        f32x4 v3 = ldT(s3);
        acc += v0; acc += v1; acc += v2; acc += v3;
    }
    for (; e < e1; e++) acc += ldT(colsrc[e]);
    u16x4 h;
#pragma unroll
    for (int j = 0; j < 4; j++) h[j] = f32_to_bf16(acc[j]);
    *reinterpret_cast<u16x4*>(Phi + (size_t)n * DIM + c) = h;
}

// ---------------- convert: Phi = bf16(relu(bf16Y*a + c)) ----------------
__global__ void convert_kernel(const unsigned short* __restrict__ Yb,
                               const float* __restrict__ pa, const float* __restrict__ pc,
                               unsigned short* __restrict__ Phi, int total8) {
    int i = blockIdx.x * blockDim.x + threadIdx.x;
    int stride = gridDim.x * blockDim.x;
    for (; i < total8; i += stride) {
        int cb = (i & 63) * 8;
        u16x8 y = *reinterpret_cast<const u16x8*>(Yb + (size_t)i * 8);
        u16x8 h;
#pragma unroll
        for (int j = 0; j < 8; j++) {
            float f = fmaxf(bf16_to_f32(y[j]) * pa[cb + j] + pc[cb + j], 0.f);
            h[j] = f32_to_bf16(f);
        }
        *reinterpret_cast<u16x8*>(Phi + (size_t)i * 8) = h;
    }
}

// ---------------- GEMM: 256x128, BK=32, dbuf. OUT=0: bf16 Y; OUT=1: fp32 Y ----------
template<int OUT>
__global__ __launch_bounds__(256, 2)
void gemm_kernel(const unsigned short* __restrict__ Ahi,
                 const unsigned short* __restrict__ Bhi,
                 const unsigned short* __restrict__ Blo,
                 const float* __restrict__ bias,
                 unsigned short* __restrict__ Yb, float* __restrict__ Yf,
                 float* __restrict__ ssum, float* __restrict__ ssq,
                 int M) {
    __shared__ unsigned short lds[2 * LDS_BUF];   // 64 KB

    const int tid = threadIdx.x;
    const int lane = tid & 63;
    const int wave = tid >> 6;
    const int wm = wave >> 1, wn = wave & 1;

    const int b = blockIdx.x;
    const int xcd = b & 7;
    const int slot_ = b >> 3;
    const int g = (slot_ >> 2) * 8 + xcd;
    const int j = slot_ & 3;
    const int m0 = g * BM;
    const int n0 = j * BN;

    const int srow = lane >> 2;
    const int sc = lane & 3;

    const int r15 = lane & 15;
    const int q = lane >> 4;
    const int rslot = ((q ^ ((r15 >> 1) & 3))) * 8;

    f32x4 acc[8][4];
#pragma unroll
    for (int i = 0; i < 8; i++)
#pragma unroll
        for (int jj = 0; jj < 4; jj++) acc[i][jj] = (f32x4){0.f, 0.f, 0.f, 0.f};

    auto STAGE = [&](int bufb, int kt) {
        unsigned short* L = lds + bufb * LDS_BUF;
#pragma unroll
        for (int i = 0; i < 4; i++) {
            int r = wave * 64 + i * 16 + srow;
            int colc = sc ^ ((r >> 1) & 3);
            gl_lds16(Ahi + (size_t)(m0 + r) * DIM + kt + colc * 8,
                     L + LDS_A + wave * 2048 + i * 512);
        }
#pragma unroll
        for (int i = 0; i < 2; i++) {
            int r = wave * 32 + i * 16 + srow;
            int colc = sc ^ ((r >> 1) & 3);
            size_t go = (size_t)(n0 + r) * DIM + kt + colc * 8;
            gl_lds16(Bhi + go, L + LDS_BH + wave * 1024 + i * 512);
            gl_lds16(Blo + go, L + LDS_BL + wave * 1024 + i * 512);
        }
    };

    STAGE(0, 0);
    __syncthreads();

    int buf = 0;
    for (int t = 0; t < DIM / BK; t++) {
        if (t < DIM / BK - 1) STAGE(buf ^ 1, (t + 1) * BK);
        unsigned short* L = lds + buf * LDS_BUF;
        bf16x8 bh[4], bl[4];
#pragma unroll
        for (int nf = 0; nf < 4; nf++) {
            int rb = wn * 64 + nf * 16 + r15;
            bh[nf] = *reinterpret_cast<const bf16x8*>(&L[LDS_BH + rb * 32 + rslot]);
            bl[nf] = *reinterpret_cast<const bf16x8*>(&L[LDS_BL + rb * 32 + rslot]);
        }
#pragma unroll
        for (int mf = 0; mf < 8; mf++) {
            int ra = wm * 128 + mf * 16 + r15;
            bf16x8 a = *reinterpret_cast<const bf16x8*>(&L[LDS_A + ra * 32 + rslot]);
#pragma unroll
            for (int nf = 0; nf < 4; nf++) {
                acc[mf][nf] = __builtin_amdgcn_mfma_f32_16x16x32_bf16(a, bl[nf], acc[mf][nf], 0, 0, 0);
                acc[mf][nf] = __builtin_amdgcn_mfma_f32_16x16x32_bf16(a, bh[nf], acc[mf][nf], 0, 0, 0);
            }
        }
        __syncthreads();
        buf ^= 1;
    }

    // epilogue: bias add, store (bf16 or fp32), column stats from exact fp32 accs
    const int ln16 = lane & 15;
    const int lg = lane >> 4;
#pragma unroll
    for (int nf = 0; nf < 4; nf++) {
        int col = n0 + wn * 64 + nf * 16 + ln16;
        float bv = bias[col];
        float s = 0.f, qq = 0.f;
#pragma unroll
        for (int mf = 0; mf < 8; mf++) {
#pragma unroll
            for (int r = 0; r < 4; r++) {
                int row = m0 + wm * 128 + mf * 16 + lg * 4 + r;
                if (row < M) {
                    float v = acc[mf][nf][r] + bv;
                    if (OUT == 0)
                        Yb[(size_t)row * DIM + col] = f32_to_bf16(v);
                    else
                        Yf[(size_t)row * DIM + col] = v;
                    s += v; qq += v * v;
                }
            }
        }
        s += __shfl_xor(s, 16);
        s += __shfl_xor(s, 32);
        qq += __shfl_xor(qq, 16);
        qq += __shfl_xor(qq, 32);
        if (lg == 0) {
            atomicAdd(&ssum[col], s);
            atomicAdd(&ssq[col], qq);
        }
    }
}

// ---------------- column stats of u = relu?(Y*a + c); optional in-place bf16 U store ----
// BF=1: Y is bf16 (Yb); BF=0: Y is fp32 (Yf). STORE=1: U[idx] = bf16(u) (U may == Yb).
template<int RELU, int STORE, int BF>
__global__ void ustats_kernel(const float* __restrict__ Yf,
                              const unsigned short* __restrict__ Yb,
                              const float* __restrict__ pa, const float* __restrict__ pc,
                              float* __restrict__ ssum, float* __restrict__ ssq,
                              unsigned short* __restrict__ U,
                              int M, int chunk) {
    int d = blockIdx.x * blockDim.x + threadIdx.x;
    int r0 = blockIdx.y * chunk;
    int r1 = r0 + chunk; if (r1 > M) r1 = M;
    float a = pa[d], c = pc[d];
    float s = 0.f, q = 0.f;
    for (int r = r0; r < r1; r++) {
        size_t idx = (size_t)r * DIM + d;
        float y = BF ? bf16_to_f32(Yb[idx]) : Yf[idx];
        float v = y * a + c;
        if (RELU) v = fmaxf(v, 0.f);
        s += v; q += v * v;
        if (STORE) U[idx] = f32_to_bf16(v);
    }
    atomicAdd(&ssum[d], s);
    atomicAdd(&ssq[d], q);
}

// ---------------- BN params ----------------
__global__ void params_kernel(const float* __restrict__ ssum, const float* __restrict__ ssq,
                              const float* __restrict__ g, const float* __restrict__ b,
                              float* __restrict__ pa, float* __restrict__ pc, float invN) {
    int d = threadIdx.x + blockIdx.x * blockDim.x;
    float m = ssum[d] * invN;
    float var = ssq[d] * invN - m * m;
    var = fmaxf(var, 0.f);
    float s = rsqrtf(var + 1e-5f);
    float a = g[d] * s;
    pa[d] = a;
    pc[d] = b[d] - m * a;
}

// ---------------- final in-place: out = (out*a2+c2)*a3+c3 ----------------
__global__ void finalize_kernel(float* __restrict__ Y,
                                const float* __restrict__ pa2, const float* __restrict__ pc2,
                                const float* __restrict__ pa3, const float* __restrict__ pc3,
                                int total4) {
    int i = blockIdx.x * blockDim.x + threadIdx.x;
    int stride = gridDim.x * blockDim.x;
    for (; i < total4; i += stride) {
        int c = (i & 127) * 4;
        f32x4 v = *reinterpret_cast<f32x4*>(Y + (size_t)i * 4);
#pragma unroll
        for (int j = 0; j < 4; j++) {
            float f = v[j] * pa2[c + j] + pc2[c + j];
            v[j] = f * pa3[c + j] + pc3[c + j];
        }
        *reinterpret_cast<f32x4*>(Y + (size_t)i * 4) = v;
    }
}

extern "C" void kernel_launch(void* const* d_in, const int* in_sizes, int n_in,
                              void* d_out, int out_size, void* d_ws, size_t ws_size,
                              hipStream_t stream) {
    const float* x   = (const float*)d_in[0];
    const int*   ei  = (const int*)d_in[1];
    const float* W1  = (const float*)d_in[2];
    const float* b1  = (const float*)d_in[3];
    const float* g1  = (const float*)d_in[4];
    const float* be1 = (const float*)d_in[5];
    const float* W2  = (const float*)d_in[6];
    const float* b2  = (const float*)d_in[7];
    const float* g2  = (const float*)d_in[8];
    const float* be2 = (const float*)d_in[9];
    const float* ng  = (const float*)d_in[10];
    const float* nb  = (const float*)d_in[11];

    const int N = in_sizes[0] / DIM;
    const int E = in_sizes[1] / 2;

    char* ws = (char*)d_ws;
    size_t off = 0;
    auto alloc = [&](size_t bytes) -> void* {
        void* p = ws + off;
        off += (bytes + 255) & ~(size_t)255;
        return p;
    };
    unsigned short* Phi = (unsigned short*)alloc((size_t)N * DIM * 2);
    unsigned short* Xbf = (unsigned short*)alloc((size_t)N * DIM * 2);   // absorbs pad-panel OOB reads
    unsigned short* Ybf = (unsigned short*)alloc((size_t)N * DIM * 2);   // y1 -> y2 -> U (in-place)
    unsigned short* Whi = (unsigned short*)alloc(6ull * DIM * DIM * 2);
    unsigned short* Wlo = (unsigned short*)alloc(6ull * DIM * DIM * 2);
    int* rowptr = (int*)alloc((size_t)(N + 1) * 4);
    int* counts = (int*)alloc((size_t)N * 4);
    int* cursor = (int*)alloc((size_t)N * 4);
    int* colsrc = (int*)alloc((size_t)E * 4);
    int* bsum   = (int*)alloc(1024 * 4);
    float* stats = (float*)alloc(9ull * 1024 * 4);
    float* prm = (float*)alloc(6ull * DIM * 4);

    float* Yout = (float*)d_out;
    float* pa1 = prm,         *pc1 = prm + DIM;
    float* pa2 = prm + 2*DIM, *pc2 = prm + 3*DIM;
    float* pa3 = prm + 4*DIM, *pc3 = prm + 5*DIM;

    hipMemsetAsync(counts, 0, (size_t)N * 4, stream);
    hipMemsetAsync(stats, 0, 9ull * 1024 * 4, stream);

    const int NBs = (N + 255) / 256;

    wprep<<<1536, 256, 0, stream>>>(W1, W2, Whi, Wlo);
    xprep<<<2048, 256, 0, stream>>>(x, Xbf, N * DIM / 8);
    csr_count<<<(E + 255) / 256, 256, 0, stream>>>(ei, counts, E);
    scan1<<<NBs, 256, 0, stream>>>(counts, rowptr, bsum, N);
    scan2<<<1, 256, 0, stream>>>(bsum, NBs);
    scan3<<<NBs, 256, 0, stream>>>(bsum, rowptr, cursor, N, E);
    csr_fill<<<(E + 255) / 256, 256, 0, stream>>>(ei, cursor, colsrc, E);

    const float invN = 1.0f / (float)N;
    const int Gm = (((N + BM - 1) / BM) + 7) & ~7;
    const int gemm_blocks = Gm * 4;
    const int uchunk = (N + 199) / 200;
    const int total8 = N * DIM / 8;

    for (int l = 0; l < NLAYERS; l++) {
        float* st1 = stats + (size_t)l * 3 * 1024;
        float* st2 = st1 + 1024;
        float* st3 = st2 + 1024;
        if (l == 0)
            agg_b<0><<<N, 128, 0, stream>>>(Xbf, rowptr, colsrc, nullptr, nullptr, Phi, N);
        else
            agg_b<1><<<N, 128, 0, stream>>>(Ybf, rowptr, colsrc, pa3, pc3, Phi, N);
        // gemm1 -> bf16 y1
        gemm_kernel<0><<<gemm_blocks, 256, 0, stream>>>(Phi,
            Whi + (size_t)(l * 2) * DIM * DIM, Wlo + (size_t)(l * 2) * DIM * DIM,
            b1 + l * DIM, Ybf, nullptr, st1, st1 + 512, N);
        params_kernel<<<1, 512, 0, stream>>>(st1, st1 + 512, g1 + l * DIM, be1 + l * DIM,
                                             pa1, pc1, invN);
        convert_kernel<<<2048, 256, 0, stream>>>(Ybf, pa1, pc1, Phi, total8);
        if (l < NLAYERS - 1) {
            // gemm2 -> bf16 y2 (overwrites dead y1)
            gemm_kernel<0><<<gemm_blocks, 256, 0, stream>>>(Phi,
                Whi + (size_t)(l * 2 + 1) * DIM * DIM, Wlo + (size_t)(l * 2 + 1) * DIM * DIM,
                b2 + l * DIM, Ybf, nullptr, st2, st2 + 512, N);
            params_kernel<<<1, 512, 0, stream>>>(st2, st2 + 512, g2 + l * DIM, be2 + l * DIM,
                                                 pa2, pc2, invN);
            // stats of u + in-place U store (u = relu(bn2(y2)))
            ustats_kernel<1, 1, 1><<<dim3(2, 200), 256, 0, stream>>>(nullptr, Ybf, pa2, pc2,
                                                                     st3, st3 + 512, Ybf,
                                                                     N, uchunk);
        } else {
            // final gemm2 -> fp32 Yout (= d_out)
            gemm_kernel<1><<<gemm_blocks, 256, 0, stream>>>(Phi,
                Whi + (size_t)(l * 2 + 1) * DIM * DIM, Wlo + (size_t)(l * 2 + 1) * DIM * DIM,
                b2 + l * DIM, nullptr, Yout, st2, st2 + 512, N);
            params_kernel<<<1, 512, 0, stream>>>(st2, st2 + 512, g2 + l * DIM, be2 + l * DIM,
                                                 pa2, pc2, invN);
            ustats_kernel<0, 0, 0><<<dim3(2, 200), 256, 0, stream>>>(Yout, nullptr, pa2, pc2,
                                                                     st3, st3 + 512, nullptr,
                                                                     N, uchunk);
        }
        params_kernel<<<1, 512, 0, stream>>>(st3, st3 + 512, ng + l * DIM, nb + l * DIM,
                                             pa3, pc3, invN);
    }
    finalize_kernel<<<2048, 256, 0, stream>>>(Yout, pa2, pc2, pa3, pc3, N * DIM / 4);
}

// Round 16
// 1269.013 us; speedup vs baseline: 1.7553x; 1.0766x over previous
//
#include <hip/hip_runtime.h>
#include <cstdint>
#include <cstddef>

#define DIM 512
#define NLAYERS 3
#define BM 256
#define BN 128
#define BK 32
#define LDS_A 0
#define LDS_BH 8192
#define LDS_BL 12288
#define LDS_BUF 16384
#define BN_EPS 1e-5f

typedef float f32x4 __attribute__((ext_vector_type(4)));
typedef short bf16x8 __attribute__((ext_vector_type(8)));
typedef unsigned short u16x4 __attribute__((ext_vector_type(4)));
typedef unsigned short u16x8 __attribute__((ext_vector_type(8)));

__device__ __forceinline__ unsigned short f32_to_bf16(float f) {
    unsigned u = __float_as_uint(f);
    u += 0x7fffu + ((u >> 16) & 1u);
    return (unsigned short)(u >> 16);
}
__device__ __forceinline__ float bf16_to_f32(unsigned short h) {
    return __uint_as_float(((unsigned)h) << 16);
}

__device__ __forceinline__ void gl_lds16(const unsigned short* g, unsigned short* l) {
    __builtin_amdgcn_global_load_lds(
        (const __attribute__((address_space(1))) void*)g,
        (__attribute__((address_space(3))) void*)l,
        16, 0, 0);
}

// a = g*rsqrt(var+eps), c = beta - mean*a  from raw sums
__device__ __forceinline__ void bn_params(float ssum, float ssq, float g, float b,
                                          float invN, float& a, float& c) {
    float m = ssum * invN;
    float var = fmaxf(ssq * invN - m * m, 0.f);
    a = g * rsqrtf(var + BN_EPS);
    c = b - m * a;
}

// ---------------- CSR build ----------------
__global__ void csr_count(const int* __restrict__ ei, int* __restrict__ counts, int E) {
    int e = blockIdx.x * 256 + threadIdx.x;
    if (e < E) atomicAdd(&counts[ei[E + e]], 1);
}

__global__ void scan1(const int* __restrict__ counts, int* __restrict__ rowptr,
                      int* __restrict__ bsum, int N) {
    __shared__ int sh[256];
    int t = threadIdx.x;
    int i = blockIdx.x * 256 + t;
    int v = (i < N) ? counts[i] : 0;
    sh[t] = v;
    __syncthreads();
    for (int d = 1; d < 256; d <<= 1) {
        int u = (t >= d) ? sh[t - d] : 0;
        __syncthreads();
        sh[t] += u;
        __syncthreads();
    }
    if (i < N) rowptr[i] = sh[t] - v;
    if (t == 255) bsum[blockIdx.x] = sh[255];
}

__global__ void scan2(int* __restrict__ bsum, int NB) {
    __shared__ int sh[256];
    int t = threadIdx.x;
    int v = (t < NB) ? bsum[t] : 0;
    sh[t] = v;
    __syncthreads();
    for (int d = 1; d < 256; d <<= 1) {
        int u = (t >= d) ? sh[t - d] : 0;
        __syncthreads();
        sh[t] += u;
        __syncthreads();
    }
    if (t < NB) bsum[t] = sh[t] - v;
}

__global__ void scan3(const int* __restrict__ bsum, int* __restrict__ rowptr,
                      int* __restrict__ cursor, int N, int E) {
    int i = blockIdx.x * 256 + threadIdx.x;
    if (i < N) {
        int v = rowptr[i] + bsum[blockIdx.x];
        rowptr[i] = v;
        cursor[i] = v;
    }
    if (blockIdx.x == 0 && threadIdx.x == 0) rowptr[N] = E;
}

__global__ void csr_fill(const int* __restrict__ ei, int* __restrict__ cursor,
                         int* __restrict__ colsrc, int E) {
    int e = blockIdx.x * 256 + threadIdx.x;
    if (e < E) {
        int s = ei[e], d = ei[E + e];
        int p = atomicAdd(&cursor[d], 1);
        colsrc[p] = s;
    }
}

// ---------------- weight prep ----------------
__global__ void wprep(const float* __restrict__ W1, const float* __restrict__ W2,
                      unsigned short* __restrict__ Whi, unsigned short* __restrict__ Wlo) {
    int id = blockIdx.x * 256 + threadIdx.x;
    int mat = id >> 16;
    int k4 = (id >> 9) & 127;
    int n = id & 511;
    const float* W = (mat & 1) ? W2 : W1;
    const float* base = W + (size_t)(mat >> 1) * DIM * DIM;
    u16x4 h, l;
#pragma unroll
    for (int j = 0; j < 4; j++) {
        float v = base[(size_t)(k4 * 4 + j) * DIM + n];
        unsigned short hh = f32_to_bf16(v);
        h[j] = hh;
        l[j] = f32_to_bf16(v - bf16_to_f32(hh));
    }
    size_t o = ((size_t)mat * DIM + n) * DIM + k4 * 4;
    *reinterpret_cast<u16x4*>(Whi + o) = h;
    *reinterpret_cast<u16x4*>(Wlo + o) = l;
}

// ---------------- xprep: Xbf = bf16(x) ----------------
__global__ void xprep(const float* __restrict__ X, unsigned short* __restrict__ Xbf,
                      int total8) {
    int i = blockIdx.x * blockDim.x + threadIdx.x;
    int stride = gridDim.x * blockDim.x;
    for (; i < total8; i += stride) {
        f32x4 v0 = *reinterpret_cast<const f32x4*>(X + (size_t)i * 8);
        f32x4 v1 = *reinterpret_cast<const f32x4*>(X + (size_t)i * 8 + 4);
        u16x8 h;
#pragma unroll
        for (int j = 0; j < 4; j++) h[j] = f32_to_bf16(v0[j]);
#pragma unroll
        for (int j = 0; j < 4; j++) h[4 + j] = f32_to_bf16(v1[j]);
        __builtin_nontemporal_store(h, reinterpret_cast<u16x8*>(Xbf + (size_t)i * 8));
    }
}

// ---------------- aggregation over bf16 rows -> A-hi plane ----------------
// MODE 0: T = identity.  MODE 1: T(v) = relu(v*a3+c3), params inlined from st3.
template<int MODE>
__global__ void agg_b(const unsigned short* __restrict__ U,
                      const int* __restrict__ rowptr, const int* __restrict__ colsrc,
                      const float* __restrict__ s3sum, const float* __restrict__ s3sq,
                      const float* __restrict__ ngl, const float* __restrict__ nbl,
                      float invN,
                      unsigned short* __restrict__ Phi, int N) {
    int n = blockIdx.x;
    int c = threadIdx.x * 4;
    f32x4 a3, c3;
    if (MODE) {
#pragma unroll
        for (int j = 0; j < 4; j++) {
            float a, cc;
            bn_params(s3sum[c + j], s3sq[c + j], ngl[c + j], nbl[c + j], invN, a, cc);
            a3[j] = a; c3[j] = cc;
        }
    }
    auto ldT = [&](int r) -> f32x4 {
        u16x4 u = *reinterpret_cast<const u16x4*>(U + (size_t)r * DIM + c);
        f32x4 v;
#pragma unroll
        for (int j = 0; j < 4; j++) {
            float f = bf16_to_f32(u[j]);
            v[j] = MODE ? fmaxf(f * a3[j] + c3[j], 0.f) : f;
        }
        return v;
    };
    f32x4 acc = ldT(n);
    int e0 = rowptr[n], e1 = rowptr[n + 1];
    int e = e0;
    for (; e + 4 <= e1; e += 4) {
        int s0 = colsrc[e], s1 = colsrc[e + 1], s2 = colsrc[e + 2], s3 = colsrc[e + 3];
        f32x4 v0 = ldT(s0);
        f32x4 v1 = ldT(s1);
        f32x4 v2 = ldT(s2);
        f32x4 v3 = ldT(s3);
        acc += v0; acc += v1; acc += v2; acc += v3;
    }
    for (; e < e1; e++) acc += ldT(colsrc[e]);
    u16x4 h;
#pragma unroll
    for (int j = 0; j < 4; j++) h[j] = f32_to_bf16(acc[j]);
    *reinterpret_cast<u16x4*>(Phi + (size_t)n * DIM + c) = h;
}

// ---------------- convert: Phi = bf16(relu(bf16Y*a1 + c1)), params inlined ----------------
__global__ void convert_kernel(const unsigned short* __restrict__ Yb,
                               const float* __restrict__ s1sum, const float* __restrict__ s1sq,
                               const float* __restrict__ g1l, const float* __restrict__ be1l,
                               float invN,
                               unsigned short* __restrict__ Phi, int total8) {
    __shared__ float spa[DIM], spc[DIM];
    for (int d = threadIdx.x; d < DIM; d += 256) {
        float a, c;
        bn_params(s1sum[d], s1sq[d], g1l[d], be1l[d], invN, a, c);
        spa[d] = a; spc[d] = c;
    }
    __syncthreads();
    int i = blockIdx.x * blockDim.x + threadIdx.x;
    int stride = gridDim.x * blockDim.x;
    for (; i < total8; i += stride) {
        int cb = (i & 63) * 8;
        u16x8 y = *reinterpret_cast<const u16x8*>(Yb + (size_t)i * 8);
        u16x8 h;
#pragma unroll
        for (int j = 0; j < 8; j++) {
            float f = fmaxf(bf16_to_f32(y[j]) * spa[cb + j] + spc[cb + j], 0.f);
            h[j] = f32_to_bf16(f);
        }
        *reinterpret_cast<u16x8*>(Phi + (size_t)i * 8) = h;
    }
}

// ---------------- GEMM: 256x128, BK=32, dbuf, bf16 out + column stats ----------
__global__ __launch_bounds__(256, 2)
void gemm_kernel(const unsigned short* __restrict__ Ahi,
                 const unsigned short* __restrict__ Bhi,
                 const unsigned short* __restrict__ Blo,
                 const float* __restrict__ bias,
                 unsigned short* __restrict__ Yb,
                 float* __restrict__ ssum, float* __restrict__ ssq,
                 int M) {
    __shared__ unsigned short lds[2 * LDS_BUF];   // 64 KB

    const int tid = threadIdx.x;
    const int lane = tid & 63;
    const int wave = tid >> 6;
    const int wm = wave >> 1, wn = wave & 1;

    const int b = blockIdx.x;
    const int xcd = b & 7;
    const int slot_ = b >> 3;
    const int g = (slot_ >> 2) * 8 + xcd;
    const int j = slot_ & 3;
    const int m0 = g * BM;
    const int n0 = j * BN;

    const int srow = lane >> 2;
    const int sc = lane & 3;

    const int r15 = lane & 15;
    const int q = lane >> 4;
    const int rslot = ((q ^ ((r15 >> 1) & 3))) * 8;

    f32x4 acc[8][4];
#pragma unroll
    for (int i = 0; i < 8; i++)
#pragma unroll
        for (int jj = 0; jj < 4; jj++) acc[i][jj] = (f32x4){0.f, 0.f, 0.f, 0.f};

    auto STAGE = [&](int bufb, int kt) {
        unsigned short* L = lds + bufb * LDS_BUF;
#pragma unroll
        for (int i = 0; i < 4; i++) {
            int r = wave * 64 + i * 16 + srow;
            int colc = sc ^ ((r >> 1) & 3);
            gl_lds16(Ahi + (size_t)(m0 + r) * DIM + kt + colc * 8,
                     L + LDS_A + wave * 2048 + i * 512);
        }
#pragma unroll
        for (int i = 0; i < 2; i++) {
            int r = wave * 32 + i * 16 + srow;
            int colc = sc ^ ((r >> 1) & 3);
            size_t go = (size_t)(n0 + r) * DIM + kt + colc * 8;
            gl_lds16(Bhi + go, L + LDS_BH + wave * 1024 + i * 512);
            gl_lds16(Blo + go, L + LDS_BL + wave * 1024 + i * 512);
        }
    };

    STAGE(0, 0);
    __syncthreads();

    int buf = 0;
    for (int t = 0; t < DIM / BK; t++) {
        if (t < DIM / BK - 1) STAGE(buf ^ 1, (t + 1) * BK);
        unsigned short* L = lds + buf * LDS_BUF;
        bf16x8 bh[4], bl[4];
#pragma unroll
        for (int nf = 0; nf < 4; nf++) {
            int rb = wn * 64 + nf * 16 + r15;
            bh[nf] = *reinterpret_cast<const bf16x8*>(&L[LDS_BH + rb * 32 + rslot]);
            bl[nf] = *reinterpret_cast<const bf16x8*>(&L[LDS_BL + rb * 32 + rslot]);
        }
#pragma unroll
        for (int mf = 0; mf < 8; mf++) {
            int ra = wm * 128 + mf * 16 + r15;
            bf16x8 a = *reinterpret_cast<const bf16x8*>(&L[LDS_A + ra * 32 + rslot]);
#pragma unroll
            for (int nf = 0; nf < 4; nf++) {
                acc[mf][nf] = __builtin_amdgcn_mfma_f32_16x16x32_bf16(a, bl[nf], acc[mf][nf], 0, 0, 0);
                acc[mf][nf] = __builtin_amdgcn_mfma_f32_16x16x32_bf16(a, bh[nf], acc[mf][nf], 0, 0, 0);
            }
        }
        __syncthreads();
        buf ^= 1;
    }

    const int ln16 = lane & 15;
    const int lg = lane >> 4;
#pragma unroll
    for (int nf = 0; nf < 4; nf++) {
        int col = n0 + wn * 64 + nf * 16 + ln16;
        float bv = bias[col];
        float s = 0.f, qq = 0.f;
#pragma unroll
        for (int mf = 0; mf < 8; mf++) {
#pragma unroll
            for (int r = 0; r < 4; r++) {
                int row = m0 + wm * 128 + mf * 16 + lg * 4 + r;
                if (row < M) {
                    float v = acc[mf][nf][r] + bv;
                    Yb[(size_t)row * DIM + col] = f32_to_bf16(v);
                    s += v; qq += v * v;
                }
            }
        }
        s += __shfl_xor(s, 16);
        s += __shfl_xor(s, 32);
        qq += __shfl_xor(qq, 16);
        qq += __shfl_xor(qq, 32);
        if (lg == 0) {
            atomicAdd(&ssum[col], s);
            atomicAdd(&ssq[col], qq);
        }
    }
}

// ---------------- ustats (l<2 only): u = relu(bn2(y2)), in-place U store + st3 ----------
__global__ void ustats_kernel(const unsigned short* __restrict__ Yb,
                              const float* __restrict__ s2sum, const float* __restrict__ s2sq,
                              const float* __restrict__ g2l, const float* __restrict__ be2l,
                              float invN,
                              float* __restrict__ s3sum, float* __restrict__ s3sq,
                              unsigned short* __restrict__ U,
                              int M, int chunk) {
    int d = blockIdx.x * blockDim.x + threadIdx.x;
    float a, c;
    bn_params(s2sum[d], s2sq[d], g2l[d], be2l[d], invN, a, c);
    int r0 = blockIdx.y * chunk;
    int r1 = r0 + chunk; if (r1 > M) r1 = M;
    float s = 0.f, q = 0.f;
    for (int r = r0; r < r1; r++) {
        size_t idx = (size_t)r * DIM + d;
        float v = fmaxf(bf16_to_f32(Yb[idx]) * a + c, 0.f);
        s += v; q += v * v;
        U[idx] = f32_to_bf16(v);
    }
    atomicAdd(&s3sum[d], s);
    atomicAdd(&s3sq[d], q);
}

// ---------------- params_final: last layer, analytic BN3 stats (no relu between) -------
// u = a2*y + c2  ->  ssum_u = a2*ssum_y + N*c2 ; var_u = a2^2 * var_y  (exact)
__global__ void params_final(const float* __restrict__ s2sum, const float* __restrict__ s2sq,
                             const float* __restrict__ g2l, const float* __restrict__ be2l,
                             const float* __restrict__ ngl, const float* __restrict__ nbl,
                             float invN,
                             float* __restrict__ pa2, float* __restrict__ pc2,
                             float* __restrict__ pa3, float* __restrict__ pc3) {
    int d = threadIdx.x;
    float a2, c2;
    bn_params(s2sum[d], s2sq[d], g2l[d], be2l[d], invN, a2, c2);
    float m_y = s2sum[d] * invN;
    float var_y = fmaxf(s2sq[d] * invN - m_y * m_y, 0.f);
    float m_u = a2 * m_y + c2;
    float var_u = a2 * a2 * var_y;
    float a3 = ngl[d] * rsqrtf(var_u + BN_EPS);
    float c3 = nbl[d] - m_u * a3;
    pa2[d] = a2; pc2[d] = c2;
    pa3[d] = a3; pc3[d] = c3;
}

// ---------------- finalize: out_f32 = (bf16y*a2+c2)*a3+c3 ----------------
__global__ void finalize_kernel(const unsigned short* __restrict__ Yb,
                                const float* __restrict__ pa2, const float* __restrict__ pc2,
                                const float* __restrict__ pa3, const float* __restrict__ pc3,
                                float* __restrict__ out, int total4) {
    int i = blockIdx.x * blockDim.x + threadIdx.x;
    int stride = gridDim.x * blockDim.x;
    for (; i < total4; i += stride) {
        int c = (i & 127) * 4;
        u16x4 y = *reinterpret_cast<const u16x4*>(Yb + (size_t)i * 4);
        f32x4 v;
#pragma unroll
        for (int j = 0; j < 4; j++) {
            float f = bf16_to_f32(y[j]) * pa2[c + j] + pc2[c + j];
            v[j] = f * pa3[c + j] + pc3[c + j];
        }
        *reinterpret_cast<f32x4*>(out + (size_t)i * 4) = v;
    }
}

extern "C" void kernel_launch(void* const* d_in, const int* in_sizes, int n_in,
                              void* d_out, int out_size, void* d_ws, size_t ws_size,
                              hipStream_t stream) {
    const float* x   = (const float*)d_in[0];
    const int*   ei  = (const int*)d_in[1];
    const float* W1  = (const float*)d_in[2];
    const float* b1  = (const float*)d_in[3];
    const float* g1  = (const float*)d_in[4];
    const float* be1 = (const float*)d_in[5];
    const float* W2  = (const float*)d_in[6];
    const float* b2  = (const float*)d_in[7];
    const float* g2  = (const float*)d_in[8];
    const float* be2 = (const float*)d_in[9];
    const float* ng  = (const float*)d_in[10];
    const float* nb  = (const float*)d_in[11];

    const int N = in_sizes[0] / DIM;
    const int E = in_sizes[1] / 2;

    char* ws = (char*)d_ws;
    size_t off = 0;
    auto alloc = [&](size_t bytes) -> void* {
        void* p = ws + off;
        off += (bytes + 255) & ~(size_t)255;
        return p;
    };
    unsigned short* Phi = (unsigned short*)alloc((size_t)N * DIM * 2);
    unsigned short* Xbf = (unsigned short*)alloc((size_t)N * DIM * 2);   // absorbs pad-panel OOB reads
    unsigned short* Ybf = (unsigned short*)alloc((size_t)N * DIM * 2);   // y1 -> y2 -> U (in-place)
    unsigned short* Whi = (unsigned short*)alloc(6ull * DIM * DIM * 2);
    unsigned short* Wlo = (unsigned short*)alloc(6ull * DIM * DIM * 2);
    int* rowptr = (int*)alloc((size_t)(N + 1) * 4);
    int* counts = (int*)alloc((size_t)N * 4);
    int* cursor = (int*)alloc((size_t)N * 4);
    int* colsrc = (int*)alloc((size_t)E * 4);
    int* bsum   = (int*)alloc(1024 * 4);
    float* stats = (float*)alloc(9ull * 1024 * 4);
    float* prm = (float*)alloc(4ull * DIM * 4);

    float* Yout = (float*)d_out;
    float* pa2 = prm,          *pc2 = prm + DIM;
    float* pa3 = prm + 2*DIM,  *pc3 = prm + 3*DIM;

    hipMemsetAsync(counts, 0, (size_t)N * 4, stream);
    hipMemsetAsync(stats, 0, 9ull * 1024 * 4, stream);

    const int NBs = (N + 255) / 256;

    wprep<<<1536, 256, 0, stream>>>(W1, W2, Whi, Wlo);
    xprep<<<2048, 256, 0, stream>>>(x, Xbf, N * DIM / 8);
    csr_count<<<(E + 255) / 256, 256, 0, stream>>>(ei, counts, E);
    scan1<<<NBs, 256, 0, stream>>>(counts, rowptr, bsum, N);
    scan2<<<1, 256, 0, stream>>>(bsum, NBs);
    scan3<<<NBs, 256, 0, stream>>>(bsum, rowptr, cursor, N, E);
    csr_fill<<<(E + 255) / 256, 256, 0, stream>>>(ei, cursor, colsrc, E);

    const float invN = 1.0f / (float)N;
    const int Gm = (((N + BM - 1) / BM) + 7) & ~7;
    const int gemm_blocks = Gm * 4;
    const int uchunk = (N + 199) / 200;
    const int total8 = N * DIM / 8;

    for (int l = 0; l < NLAYERS; l++) {
        float* st1 = stats + (size_t)l * 3 * 1024;
        float* st2 = st1 + 1024;
        float* st3 = st2 + 1024;
        if (l == 0)
            agg_b<0><<<N, 128, 0, stream>>>(Xbf, rowptr, colsrc,
                                            nullptr, nullptr, nullptr, nullptr, invN, Phi, N);
        else {
            float* p3 = stats + (size_t)(l - 1) * 3 * 1024 + 2048;   // prev layer st3
            agg_b<1><<<N, 128, 0, stream>>>(Ybf, rowptr, colsrc,
                                            p3, p3 + 512, ng + (l - 1) * DIM, nb + (l - 1) * DIM,
                                            invN, Phi, N);
        }
        gemm_kernel<<<gemm_blocks, 256, 0, stream>>>(Phi,
            Whi + (size_t)(l * 2) * DIM * DIM, Wlo + (size_t)(l * 2) * DIM * DIM,
            b1 + l * DIM, Ybf, st1, st1 + 512, N);
        convert_kernel<<<2048, 256, 0, stream>>>(Ybf, st1, st1 + 512,
                                                 g1 + l * DIM, be1 + l * DIM, invN,
                                                 Phi, total8);
        gemm_kernel<<<gemm_blocks, 256, 0, stream>>>(Phi,
            Whi + (size_t)(l * 2 + 1) * DIM * DIM, Wlo + (size_t)(l * 2 + 1) * DIM * DIM,
            b2 + l * DIM, Ybf, st2, st2 + 512, N);
        if (l < NLAYERS - 1)
            ustats_kernel<<<dim3(2, 200), 256, 0, stream>>>(Ybf, st2, st2 + 512,
                                                            g2 + l * DIM, be2 + l * DIM, invN,
                                                            st3, st3 + 512, Ybf, N, uchunk);
    }
    {
        int l = NLAYERS - 1;
        float* st2 = stats + (size_t)l * 3 * 1024 + 1024;
        params_final<<<1, 512, 0, stream>>>(st2, st2 + 512,
                                            g2 + l * DIM, be2 + l * DIM,
                                            ng + l * DIM, nb + l * DIM, invN,
                                            pa2, pc2, pa3, pc3);
    }
    finalize_kernel<<<2048, 256, 0, stream>>>(Ybf, pa2, pc2, pa3, pc3, Yout, N * DIM / 4);
}